// Round 2
// baseline (777.888 us; speedup 1.0000x reference)
//
#include <hip/hip_runtime.h>
#include <hip/hip_bf16.h>
#include <math.h>

typedef unsigned short ushort_t;
typedef __attribute__((ext_vector_type(8))) short short8;
typedef __attribute__((ext_vector_type(4))) short short4v;
typedef __attribute__((ext_vector_type(4))) float float4v;

#define HID 1024
#define NH 8
#define DH 128
#define CHUNK 12
#define PAST 12
#define CTX 24
#define NPOS 25

__device__ __forceinline__ float bf2f(ushort_t b){
  union{unsigned int u; float f;} x; x.u = ((unsigned int)b)<<16; return x.f;
}
__device__ __forceinline__ ushort_t f2bf(float f){
  union{float f; unsigned int u;} x; x.f = f;
  unsigned int u = x.u;
  unsigned int r = u + 0x7fffu + ((u>>16)&1u);
  return (ushort_t)(r>>16);
}

// f32 -> bf16 conversion, vectorized, grid-stride (n4 = elems/4)
__global__ __launch_bounds__(256) void cvt_f2b(
    const float* __restrict__ in, ushort_t* __restrict__ out, int n4)
{
  for (int i = blockIdx.x*256 + threadIdx.x; i < n4; i += gridDim.x*256){
    float4v v = ((const float4v*)in)[i];
    short4v o;
#pragma unroll
    for (int j=0;j<4;j++) o[j] = (short)f2bf(v[j]);
    ((short4v*)out)[i] = o;
  }
}

// C[M,N] = A[M,K] @ W[N,K]^T  (bf16 in, f32 accum)
// SMODE: 0 = none, 1 = constant scale, 2 = qscale * softplus(pds[col%128])
// OUTF:  0 = bf16 out, 1 = f32 out
template<int SMODE, int OUTF>
__global__ __launch_bounds__(256) void gemm_bt(
    const ushort_t* __restrict__ A, const ushort_t* __restrict__ W,
    void* __restrict__ Cv, int M, int N, int K,
    const float* __restrict__ pds, float cscale)
{
  const int tid  = threadIdx.x;
  const int m0   = blockIdx.x * 128;
  const int n0   = blockIdx.y * 128;
  const int wave = tid >> 6, lane = tid & 63;
  const int wm = wave >> 1, wn = wave & 1;   // 2x2 waves -> 64x64 per wave
  const int lr = lane & 15;                  // frag row (A) / col (B,C)
  const int lk = lane >> 4;                  // k-group 0..3

  __shared__ ushort_t As[128][40];
  __shared__ ushort_t Bs[128][40];

  float4v acc[4][4];
#pragma unroll
  for (int i=0;i<4;i++)
#pragma unroll
    for (int j=0;j<4;j++) acc[i][j] = (float4v)0.0f;

  const int lrow = tid >> 1;            // 0..127
  const int lk0  = (tid & 1) * 16;      // 0 or 16

  for (int kt = 0; kt < K; kt += 32) {
    const ushort_t* ag = A + (size_t)(m0 + lrow)*K + kt + lk0;
    const ushort_t* bg = W + (size_t)(n0 + lrow)*K + kt + lk0;
    short8 av0 = *(const short8*)(ag);
    short8 av1 = *(const short8*)(ag+8);
    short8 bv0 = *(const short8*)(bg);
    short8 bv1 = *(const short8*)(bg+8);
    *(short8*)&As[lrow][lk0]   = av0;
    *(short8*)&As[lrow][lk0+8] = av1;
    *(short8*)&Bs[lrow][lk0]   = bv0;
    *(short8*)&Bs[lrow][lk0+8] = bv1;
    __syncthreads();

    short8 afr[4], bfr[4];
#pragma unroll
    for (int i=0;i<4;i++) afr[i] = *(const short8*)&As[wm*64 + i*16 + lr][lk*8];
#pragma unroll
    for (int j=0;j<4;j++) bfr[j] = *(const short8*)&Bs[wn*64 + j*16 + lr][lk*8];
#pragma unroll
    for (int i=0;i<4;i++)
#pragma unroll
      for (int j=0;j<4;j++)
        acc[i][j] = __builtin_amdgcn_mfma_f32_16x16x32_bf16(afr[i], bfr[j], acc[i][j], 0,0,0);
    __syncthreads();
  }

#pragma unroll
  for (int j=0;j<4;j++){
    int col = n0 + wn*64 + j*16 + lr;
    float scale = 1.0f;
    if (SMODE==1) scale = cscale;
    if (SMODE==2){ float p = pds[col & (DH-1)]; scale = cscale * log1pf(expf(p)); }
#pragma unroll
    for (int i=0;i<4;i++){
      int row = m0 + wm*64 + i*16 + lk*4;
#pragma unroll
      for (int r=0;r<4;r++){
        float val = acc[i][j][r] * scale;
        if (OUTF) ((float*)Cv)[(size_t)(row + r)*N + col] = val;
        else ((ushort_t*)Cv)[(size_t)(row + r)*N + col] = f2bf(val);
      }
    }
  }
}

// rel[25,1024] = pos_emb[25,1024] @ Wrel[1024,1024]^T   (f32 in, bf16 out)
__global__ __launch_bounds__(256) void relk_kernel(
    const float* __restrict__ pe, const float* __restrict__ Wrel,
    ushort_t* __restrict__ rel)
{
  int gid = blockIdx.x*256 + threadIdx.x;
  if (gid >= NPOS*HID) return;
  int p = gid >> 10, n = gid & 1023;
  const float* a = pe + p*HID;
  const float* w = Wrel + (size_t)n*HID;
  float s = 0.f;
  for (int k=0;k<HID;k+=4){
    float4v av = *(const float4v*)(a+k);
    float4v wv = *(const float4v*)(w+k);
#pragma unroll
    for (int u=0;u<4;u++) s += av[u]*wv[u];
  }
  rel[gid] = f2bf(s);
}

// one block per (chunk n, batch b, head h); q/k/v/rel bf16, out bf16
__global__ __launch_bounds__(256) void attn_kernel(
  const ushort_t* __restrict__ q, const ushort_t* __restrict__ k,
  const ushort_t* __restrict__ v, const ushort_t* __restrict__ rel,
  ushort_t* __restrict__ o, int S)
{
  const int n = blockIdx.x, b = blockIdx.y, h = blockIdx.z;
  const int tid = threadIdx.x;
  __shared__ float qs[CHUNK][DH+1];
  __shared__ float ks[CTX][DH+1];
  __shared__ float vs[CTX][DH+1];
  __shared__ float rs[NPOS][DH+1];
  __shared__ float ls[CHUNK][NPOS];   // logits then probs (24 cols used)

  const size_t bS = (size_t)b * S;

  for (int idx = tid; idx < CHUNK*DH; idx += 256){
    int c = idx >> 7, d = idx & 127;
    qs[c][d] = bf2f(q[(bS + n*CHUNK + c)*HID + h*DH + d]);
  }
  for (int idx = tid; idx < CTX*DH; idx += 256){
    int t = idx >> 7, d = idx & 127;
    int s = n*CHUNK - PAST + t;
    float kv = 0.f, vv = 0.f;
    if (s >= 0 && s < S){
      kv = bf2f(k[(bS + s)*HID + h*DH + d]);
      vv = bf2f(v[(bS + s)*HID + h*DH + d]);
    }
    ks[t][d] = kv; vs[t][d] = vv;
  }
  for (int idx = tid; idx < NPOS*DH; idx += 256){
    int p = idx >> 7, d = idx & 127;
    rs[p][d] = bf2f(rel[p*HID + h*DH + d]);
  }
  __syncthreads();

  // logits with fused rel-shift:  ls[c][t] = q[c].k[t] + q[r].rel[p],
  // where f=c*24+t, r=f/25, p=f%25  (exact reference _rel_shift semantics)
  for (int e = tid; e < CHUNK*CTX; e += 256){
    int c = e / CTX, t = e - c*CTX;
    int f = c*CTX + t;
    int r = f / NPOS, p = f - r*NPOS;
    float ac = 0.f, bd = 0.f;
    for (int d=0; d<DH; d++){
      ac += qs[c][d]*ks[t][d];
      bd += qs[r][d]*rs[p][d];
    }
    float x = ac + bd;
    x = 50.0f * tanhf(x * 0.02f);
    ls[c][t] = x;
  }
  __syncthreads();

  if (tid < CHUNK){
    float m = -1e30f;
#pragma unroll
    for (int t=0;t<CTX;t++) m = fmaxf(m, ls[tid][t]);
    float tmp[CTX];
    float sum = 0.f;
#pragma unroll
    for (int t=0;t<CTX;t++){ float e2 = expf(ls[tid][t]-m); tmp[t]=e2; sum += e2; }
    float inv = 1.0f/sum;
#pragma unroll
    for (int t=0;t<CTX;t++) ls[tid][t] = tmp[t]*inv;
  }
  __syncthreads();

  for (int e = tid; e < CHUNK*DH; e += 256){
    int c = e >> 7, d = e & 127;
    float s = 0.f;
#pragma unroll
    for (int t=0;t<CTX;t++) s += ls[c][t]*vs[t][d];
    o[(bS + n*CHUNK + c)*HID + h*DH + d] = f2bf(s);
  }
}

extern "C" void kernel_launch(void* const* d_in, const int* in_sizes, int n_in,
                              void* d_out, int out_size, void* d_ws, size_t ws_size,
                              hipStream_t stream)
{
  const float* hs    = (const float*)d_in[0];
  const float* pe    = (const float*)d_in[1];
  const float* Wq    = (const float*)d_in[2];
  const float* Wk    = (const float*)d_in[3];
  const float* Wv    = (const float*)d_in[4];
  const float* Wpost = (const float*)d_in[5];
  const float* Wrel  = (const float*)d_in[6];
  const float* pds   = (const float*)d_in[7];
  float* out = (float*)d_out;

  const int BS = in_sizes[0] / HID;   // B*S = 24576
  const int B  = 4;
  const int S  = BS / B;              // 6144

  const size_t per = (size_t)BS * HID;      // 25.2M elems
  const size_t wsz = (size_t)HID * HID;     // 1M elems
  ushort_t* q   = (ushort_t*)d_ws;
  ushort_t* kk  = q   + per;
  ushort_t* vv  = kk  + per;
  ushort_t* at  = vv  + per;
  ushort_t* rel = at  + per;
  ushort_t* hsb = rel + (size_t)NPOS*HID;
  ushort_t* Wqb = hsb + per;
  ushort_t* Wkb = Wqb + wsz;
  ushort_t* Wvb = Wkb + wsz;
  ushort_t* Wpb = Wvb + wsz;

  const float qsc = (float)(pow((double)DH, -0.5) / log(2.0));   // D^-0.5/ln2
  const float ksc = (float)(log(1.0 + exp(1.0)) / log(2.0));     // ln(1+e)/ln2

  // f32 -> bf16 conversions
  cvt_f2b<<<2048, 256, 0, stream>>>(hs,    hsb, (int)(per/4));
  cvt_f2b<<<1024, 256, 0, stream>>>(Wq,    Wqb, (int)(wsz/4));
  cvt_f2b<<<1024, 256, 0, stream>>>(Wk,    Wkb, (int)(wsz/4));
  cvt_f2b<<<1024, 256, 0, stream>>>(Wv,    Wvb, (int)(wsz/4));
  cvt_f2b<<<1024, 256, 0, stream>>>(Wpost, Wpb, (int)(wsz/4));

  dim3 gg(BS/128, HID/128);
  gemm_bt<2,0><<<gg, 256, 0, stream>>>(hsb, Wqb, q,  BS, HID, HID, pds, qsc);
  gemm_bt<1,0><<<gg, 256, 0, stream>>>(hsb, Wkb, kk, BS, HID, HID, nullptr, ksc);
  gemm_bt<0,0><<<gg, 256, 0, stream>>>(hsb, Wvb, vv, BS, HID, HID, nullptr, 1.0f);
  relk_kernel<<<(NPOS*HID + 255)/256, 256, 0, stream>>>(pe, Wrel, rel);
  attn_kernel<<<dim3(S/CHUNK, B, NH), 256, 0, stream>>>(q, kk, vv, rel, at, S);
  gemm_bt<0,1><<<gg, 256, 0, stream>>>(at, Wpb, out, BS, HID, HID, nullptr, 1.0f);
}

// Round 3
// 495.500 us; speedup vs baseline: 1.5699x; 1.5699x over previous
//
#include <hip/hip_runtime.h>
#include <hip/hip_bf16.h>
#include <math.h>

typedef unsigned short ushort_t;
typedef __attribute__((ext_vector_type(8))) short short8;
typedef __attribute__((ext_vector_type(4))) short s4v;
typedef __attribute__((ext_vector_type(4))) float float4v;

#define HID 1024
#define NH 8
#define DH 128
#define CHUNK 12
#define PAST 12
#define CTX 24
#define NPOS 25

__device__ __forceinline__ float bf2f(ushort_t b){
  union{unsigned int u; float f;} x; x.u = ((unsigned int)b)<<16; return x.f;
}
__device__ __forceinline__ ushort_t f2bf(float f){
  union{float f; unsigned int u;} x; x.f = f;
  unsigned int u = x.u;
  unsigned int r = u + 0x7fffu + ((u>>16)&1u);
  return (ushort_t)(r>>16);
}

// f32 -> bf16 conversion, vectorized, grid-stride (n4 = elems/4)
__global__ __launch_bounds__(256) void cvt_f2b(
    const float* __restrict__ in, ushort_t* __restrict__ out, int n4)
{
  for (int i = blockIdx.x*256 + threadIdx.x; i < n4; i += gridDim.x*256){
    float4v v = ((const float4v*)in)[i];
    s4v o;
#pragma unroll
    for (int j=0;j<4;j++) o[j] = (short)f2bf(v[j]);
    ((s4v*)out)[i] = o;
  }
}

// C[M,N] = A[M,K] @ W[N,K]^T  (bf16 in, f32 accum)  -- verified baseline
template<int SMODE, int OUTF>
__global__ __launch_bounds__(256) void gemm_bt(
    const ushort_t* __restrict__ A, const ushort_t* __restrict__ W,
    void* __restrict__ Cv, int M, int N, int K,
    const float* __restrict__ pds, float cscale)
{
  const int tid  = threadIdx.x;
  const int m0   = blockIdx.x * 128;
  const int n0   = blockIdx.y * 128;
  const int wave = tid >> 6, lane = tid & 63;
  const int wm = wave >> 1, wn = wave & 1;
  const int lr = lane & 15;
  const int lk = lane >> 4;

  __shared__ ushort_t As[128][40];
  __shared__ ushort_t Bs[128][40];

  float4v acc[4][4];
#pragma unroll
  for (int i=0;i<4;i++)
#pragma unroll
    for (int j=0;j<4;j++) acc[i][j] = (float4v)0.0f;

  const int lrow = tid >> 1;
  const int lk0  = (tid & 1) * 16;

  for (int kt = 0; kt < K; kt += 32) {
    const ushort_t* ag = A + (size_t)(m0 + lrow)*K + kt + lk0;
    const ushort_t* bg = W + (size_t)(n0 + lrow)*K + kt + lk0;
    short8 av0 = *(const short8*)(ag);
    short8 av1 = *(const short8*)(ag+8);
    short8 bv0 = *(const short8*)(bg);
    short8 bv1 = *(const short8*)(bg+8);
    *(short8*)&As[lrow][lk0]   = av0;
    *(short8*)&As[lrow][lk0+8] = av1;
    *(short8*)&Bs[lrow][lk0]   = bv0;
    *(short8*)&Bs[lrow][lk0+8] = bv1;
    __syncthreads();

    short8 afr[4], bfr[4];
#pragma unroll
    for (int i=0;i<4;i++) afr[i] = *(const short8*)&As[wm*64 + i*16 + lr][lk*8];
#pragma unroll
    for (int j=0;j<4;j++) bfr[j] = *(const short8*)&Bs[wn*64 + j*16 + lr][lk*8];
#pragma unroll
    for (int i=0;i<4;i++)
#pragma unroll
      for (int j=0;j<4;j++)
        acc[i][j] = __builtin_amdgcn_mfma_f32_16x16x32_bf16(afr[i], bfr[j], acc[i][j], 0,0,0);
    __syncthreads();
  }

#pragma unroll
  for (int j=0;j<4;j++){
    int col = n0 + wn*64 + j*16 + lr;
    float scale = 1.0f;
    if (SMODE==1) scale = cscale;
    if (SMODE==2){ float p = pds[col & (DH-1)]; scale = cscale * log1pf(expf(p)); }
#pragma unroll
    for (int i=0;i<4;i++){
      int row = m0 + wm*64 + i*16 + lk*4;
#pragma unroll
      for (int r=0;r<4;r++){
        float val = acc[i][j][r] * scale;
        if (OUTF) ((float*)Cv)[(size_t)(row + r)*N + col] = val;
        else ((ushort_t*)Cv)[(size_t)(row + r)*N + col] = f2bf(val);
      }
    }
  }
}

// rel[25,1024] = pos_emb[25,1024] @ Wrel[1024,1024]^T   (f32 in, bf16 out)
__global__ __launch_bounds__(256) void relk_kernel(
    const float* __restrict__ pe, const float* __restrict__ Wrel,
    ushort_t* __restrict__ rel)
{
  int gid = blockIdx.x*256 + threadIdx.x;
  if (gid >= NPOS*HID) return;
  int p = gid >> 10, n = gid & 1023;
  const float* a = pe + p*HID;
  const float* w = Wrel + (size_t)n*HID;
  float s = 0.f;
  for (int k=0;k<HID;k+=4){
    float4v av = *(const float4v*)(a+k);
    float4v wv = *(const float4v*)(w+k);
#pragma unroll
    for (int u=0;u<4;u++) s += av[u]*wv[u];
  }
  rel[gid] = f2bf(s);
}

// MFMA attention: block = 4 waves = 4 consecutive chunks of one (b,h).
// Shared staging of K [68][136], V^T [128][68], rel [32][136] (all bf16,
// zero-padded). Per-wave: AC = q@k^T (8 MFMA), BD = q@rel^T (8 MFMA),
// rel-shift+softcap+softmax (wave-parallel), PV (8 MFMA).
__global__ __launch_bounds__(256) void attn_kernel(
  const ushort_t* __restrict__ q, const ushort_t* __restrict__ k,
  const ushort_t* __restrict__ v, const ushort_t* __restrict__ rel,
  ushort_t* __restrict__ o, int S)
{
  const int n0 = blockIdx.x * 4;          // first chunk of this block
  const int b  = blockIdx.y, h = blockIdx.z;
  const int tid = threadIdx.x;
  const size_t bS = (size_t)b * S;

  __shared__ ushort_t ks[68][136];
  __shared__ ushort_t vt[128][68];
  __shared__ ushort_t rs[32][136];
  __shared__ float    sA[4][12][36];
  __shared__ float    sB[4][12][36];
  __shared__ ushort_t Pp[4][16][40];

  // ---- staging (zero-pad everything that can be touched) ----
  const int base = n0*CHUNK - PAST;       // global row of staged index 0
  {
    const int r0 = tid >> 4;
    const int c0 = (tid & 15) * 8;
    for (int r = r0; r < 68; r += 16){
      int s = base + r;
      short8 kv = (short8)0, vv = (short8)0;
      if (r < 60 && s >= 0 && s < S){
        kv = *(const short8*)&k[(bS + s)*HID + h*DH + c0];
        vv = *(const short8*)&v[(bS + s)*HID + h*DH + c0];
      }
      *(short8*)&ks[r][c0] = kv;
#pragma unroll
      for (int u=0;u<8;u++) vt[c0+u][r] = (ushort_t)vv[u];
    }
    for (int r = r0; r < 32; r += 16){
      short8 rv = (short8)0;
      if (r < NPOS) rv = *(const short8*)&rel[r*HID + h*DH + c0];
      *(short8*)&rs[r][c0] = rv;
    }
  }
  __syncthreads();

  const int w    = tid >> 6;
  const int lane = tid & 63;
  const int lr   = lane & 15;
  const int lg   = lane >> 4;             // 0..3

  // ---- q fragments direct from global (16B aligned per lane) ----
  int qrow = (n0 + w)*CHUNK + lr;         // rows >= chunk end give junk -> ignored
  if (qrow >= S) qrow = S - 1;
  const ushort_t* qp = q + (bS + qrow)*HID + h*DH + lg*8;
  short8 qf[4];
#pragma unroll
  for (int ks2=0; ks2<4; ks2++) qf[ks2] = *(const short8*)(qp + ks2*32);

  // ---- AC = q @ k^T  -> sA ----
#pragma unroll
  for (int t0=0; t0<2; t0++){
    float4v acc = (float4v)0.0f;
#pragma unroll
    for (int ks2=0; ks2<4; ks2++){
      short8 kf = *(const short8*)&ks[w*CHUNK + t0*16 + lr][ks2*32 + lg*8];
      acc = __builtin_amdgcn_mfma_f32_16x16x32_bf16(qf[ks2], kf, acc, 0,0,0);
    }
#pragma unroll
    for (int reg=0; reg<4; reg++){
      int cr = lg*4 + reg;
      if (cr < CHUNK) sA[w][cr][t0*16 + lr] = acc[reg];
    }
  }

  // ---- BD = q @ rel^T -> sB ----
#pragma unroll
  for (int t0=0; t0<2; t0++){
    float4v acc = (float4v)0.0f;
#pragma unroll
    for (int ks2=0; ks2<4; ks2++){
      short8 rf = *(const short8*)&rs[t0*16 + lr][ks2*32 + lg*8];
      acc = __builtin_amdgcn_mfma_f32_16x16x32_bf16(qf[ks2], rf, acc, 0,0,0);
    }
#pragma unroll
    for (int reg=0; reg<4; reg++){
      int cr = lg*4 + reg;
      if (cr < CHUNK) sB[w][cr][t0*16 + lr] = acc[reg];
    }
  }

  // ---- zero P tile (cols 0..31 of all 16 rows) ----
#pragma unroll
  for (int i=0;i<2;i++){
    int idx = i*64 + lane;        // 0..127 -> row=idx>>3, col4=(idx&7)*4
    *(s4v*)&Pp[w][idx>>3][(idx&7)*4] = (s4v)0;
  }

  // ---- rel-shift + softcap + softmax (wave-parallel, 2 rows per pass) ----
  {
    const int c2 = lane >> 5;     // 0,1
    const int t  = lane & 31;
#pragma unroll
    for (int i=0;i<6;i++){
      int c = i*2 + c2;           // 0..11
      float x = -1e30f;
      if (t < CTX){
        int f = c*CTX + t;
        int r = f / NPOS, p = f - r*NPOS;
        x = sA[w][c][t] + sB[w][r][p];
        x = 50.0f * tanhf(x * 0.02f);
      }
      float m = x;
      for (int off=16; off>=1; off>>=1) m = fmaxf(m, __shfl_xor(m, off, 32));
      float e = (t < CTX) ? expf(x - m) : 0.0f;
      float s = e;
      for (int off=16; off>=1; off>>=1) s += __shfl_xor(s, off, 32);
      if (t < CTX) Pp[w][c][t] = f2bf(e / s);
    }
  }

  // ---- PV: O[12x128] = P @ V ----
  short8 pf = *(const short8*)&Pp[w][lr][lg*8];
  const int orow_base = (n0 + w)*CHUNK;
#pragma unroll
  for (int j=0; j<8; j++){
    int d  = j*16 + lr;
    int tb = w*CHUNK + lg*8;
    s4v b0 = *(const s4v*)&vt[d][tb];
    s4v b1 = *(const s4v*)&vt[d][tb+4];
    short8 bf;
#pragma unroll
    for (int u=0;u<4;u++){ bf[u] = b0[u]; bf[u+4] = b1[u]; }
    float4v a = __builtin_amdgcn_mfma_f32_16x16x32_bf16(pf, bf, (float4v)0.0f, 0,0,0);
#pragma unroll
    for (int reg=0; reg<4; reg++){
      int cr = lg*4 + reg;
      if (cr < CHUNK)
        o[(bS + orow_base + cr)*HID + h*DH + j*16 + lr] = f2bf(a[reg]);
    }
  }
}

extern "C" void kernel_launch(void* const* d_in, const int* in_sizes, int n_in,
                              void* d_out, int out_size, void* d_ws, size_t ws_size,
                              hipStream_t stream)
{
  const float* hs    = (const float*)d_in[0];
  const float* pe    = (const float*)d_in[1];
  const float* Wq    = (const float*)d_in[2];
  const float* Wk    = (const float*)d_in[3];
  const float* Wv    = (const float*)d_in[4];
  const float* Wpost = (const float*)d_in[5];
  const float* Wrel  = (const float*)d_in[6];
  const float* pds   = (const float*)d_in[7];
  float* out = (float*)d_out;

  const int BS = in_sizes[0] / HID;   // B*S = 24576
  const int B  = 4;
  const int S  = BS / B;              // 6144
  const int nb = S / CHUNK;           // 512

  const size_t per = (size_t)BS * HID;
  const size_t wsz = (size_t)HID * HID;
  ushort_t* q   = (ushort_t*)d_ws;
  ushort_t* kk  = q   + per;
  ushort_t* vv  = kk  + per;
  ushort_t* at  = vv  + per;
  ushort_t* rel = at  + per;
  ushort_t* hsb = rel + (size_t)NPOS*HID;
  ushort_t* Wqb = hsb + per;
  ushort_t* Wkb = Wqb + wsz;
  ushort_t* Wvb = Wkb + wsz;
  ushort_t* Wpb = Wvb + wsz;

  const float qsc = (float)(pow((double)DH, -0.5) / log(2.0));   // D^-0.5/ln2
  const float ksc = (float)(log(1.0 + exp(1.0)) / log(2.0));     // ln(1+e)/ln2

  cvt_f2b<<<2048, 256, 0, stream>>>(hs,    hsb, (int)(per/4));
  cvt_f2b<<<1024, 256, 0, stream>>>(Wq,    Wqb, (int)(wsz/4));
  cvt_f2b<<<1024, 256, 0, stream>>>(Wk,    Wkb, (int)(wsz/4));
  cvt_f2b<<<1024, 256, 0, stream>>>(Wv,    Wvb, (int)(wsz/4));
  cvt_f2b<<<1024, 256, 0, stream>>>(Wpost, Wpb, (int)(wsz/4));

  dim3 gg(BS/128, HID/128);
  gemm_bt<2,0><<<gg, 256, 0, stream>>>(hsb, Wqb, q,  BS, HID, HID, pds, qsc);
  gemm_bt<1,0><<<gg, 256, 0, stream>>>(hsb, Wkb, kk, BS, HID, HID, nullptr, ksc);
  gemm_bt<0,0><<<gg, 256, 0, stream>>>(hsb, Wvb, vv, BS, HID, HID, nullptr, 1.0f);
  relk_kernel<<<(NPOS*HID + 255)/256, 256, 0, stream>>>(pe, Wrel, rel);
  attn_kernel<<<dim3(nb/4, B, NH), 256, 0, stream>>>(q, kk, vv, rel, at, S);
  gemm_bt<0,1><<<gg, 256, 0, stream>>>(at, Wpb, out, BS, HID, HID, nullptr, 1.0f);
}

// Round 4
// 478.850 us; speedup vs baseline: 1.6245x; 1.0348x over previous
//
#include <hip/hip_runtime.h>
#include <hip/hip_bf16.h>
#include <math.h>

typedef unsigned short ushort_t;
typedef __attribute__((ext_vector_type(8))) short short8;
typedef __attribute__((ext_vector_type(4))) short s4v;
typedef __attribute__((ext_vector_type(4))) float float4v;

#define HID 1024
#define NH 8
#define DH 128
#define CHUNK 12
#define PAST 12
#define CTX 24
#define NPOS 25
#define QKVW 3072

__device__ __forceinline__ float bf2f(ushort_t b){
  union{unsigned int u; float f;} x; x.u = ((unsigned int)b)<<16; return x.f;
}
__device__ __forceinline__ ushort_t f2bf(float f){
  union{float f; unsigned int u;} x; x.f = f;
  unsigned int u = x.u;
  unsigned int r = u + 0x7fffu + ((u>>16)&1u);
  return (ushort_t)(r>>16);
}

// async global->LDS, 16B per lane; LDS dest = wave-uniform base + lane*16
__device__ __forceinline__ void gload16(const ushort_t* g, ushort_t* l){
  __builtin_amdgcn_global_load_lds(
      (const __attribute__((address_space(1))) unsigned int*)g,
      (__attribute__((address_space(3))) unsigned int*)l,
      16, 0, 0);
}

// f32 -> bf16 conversion, vectorized, grid-stride (n4 = elems/4)
__global__ __launch_bounds__(256) void cvt_f2b(
    const float* __restrict__ in, ushort_t* __restrict__ out, int n4)
{
  for (int i = blockIdx.x*256 + threadIdx.x; i < n4; i += gridDim.x*256){
    float4v v = ((const float4v*)in)[i];
    s4v o;
#pragma unroll
    for (int j=0;j<4;j++) o[j] = (short)f2bf(v[j]);
    ((s4v*)out)[i] = o;
  }
}

// C[M,N] = A[M,K] @ W[N,K]^T  (bf16 in, f32 accum), m97-style:
// 128x128 tile, BK=32, linear LDS, global_load_lds width-16 staging.
// MODE: 0 = no scale, 1 = fused qkv epilogue (col<1024: qsc*softplus(pds),
//       col<2048: ksc, else 1).   OUTF: 0 = bf16 out, 1 = f32 out
template<int MODE, int OUTF>
__global__ __launch_bounds__(256) void gemm_lds(
    const ushort_t* __restrict__ A, const ushort_t* __restrict__ W,
    void* __restrict__ Cv, int M, int N, int K,
    const float* __restrict__ pds, float qsc, float ksc)
{
  const int tid  = threadIdx.x;
  const int m0   = blockIdx.x * 128;
  const int n0   = blockIdx.y * 128;
  const int w    = tid >> 6, lane = tid & 63;
  const int wm   = w >> 1, wn = w & 1;
  const int lr   = lane & 15;
  const int lg   = lane >> 4;

  __shared__ ushort_t As[128*32];
  __shared__ ushort_t Bs[128*32];

  float4v acc[4][4];
#pragma unroll
  for (int i=0;i<4;i++)
#pragma unroll
    for (int j=0;j<4;j++) acc[i][j] = (float4v)0.0f;

  const int sr = lane >> 2;        // 0..15: row within 16-row group
  const int sc = (lane & 3) * 8;   // col elems: 4 lanes cover one 64B row

  const ushort_t* Abase = A + (size_t)m0 * K;
  const ushort_t* Bbase = W + (size_t)n0 * K;

  for (int kt = 0; kt < K; kt += 32){
    // stage A,B tiles: per wave 2 insts each, 1KB per inst (16 rows x 64B)
#pragma unroll
    for (int i=0;i<2;i++){
      const int rbase = i*64 + w*16;
      gload16(Abase + (size_t)(rbase + sr)*K + kt + sc, &As[rbase*32]);
      gload16(Bbase + (size_t)(rbase + sr)*K + kt + sc, &Bs[rbase*32]);
    }
    __syncthreads();   // drains vmcnt(0) per-wave before barrier release

    short8 afr[4], bfr[4];
#pragma unroll
    for (int i=0;i<4;i++) afr[i] = *(const short8*)&As[(wm*64 + i*16 + lr)*32 + lg*8];
#pragma unroll
    for (int j=0;j<4;j++) bfr[j] = *(const short8*)&Bs[(wn*64 + j*16 + lr)*32 + lg*8];
#pragma unroll
    for (int i=0;i<4;i++)
#pragma unroll
      for (int j=0;j<4;j++)
        acc[i][j] = __builtin_amdgcn_mfma_f32_16x16x32_bf16(afr[i], bfr[j], acc[i][j], 0,0,0);
    __syncthreads();
  }

#pragma unroll
  for (int j=0;j<4;j++){
    int col = n0 + wn*64 + j*16 + lr;
    float scale = 1.0f;
    if (MODE==1){
      if (col < 1024){ float p = pds[col & (DH-1)]; scale = qsc * log1pf(expf(p)); }
      else if (col < 2048) scale = ksc;
    }
#pragma unroll
    for (int i=0;i<4;i++){
      int row = m0 + wm*64 + i*16 + lg*4;
#pragma unroll
      for (int r=0;r<4;r++){
        float val = acc[i][j][r] * scale;
        if (OUTF) ((float*)Cv)[(size_t)(row + r)*N + col] = val;
        else ((ushort_t*)Cv)[(size_t)(row + r)*N + col] = f2bf(val);
      }
    }
  }
}

// rel[25,1024] = pos_emb[25,1024] @ Wrel[1024,1024]^T   (f32 in, bf16 out)
__global__ __launch_bounds__(256) void relk_kernel(
    const float* __restrict__ pe, const float* __restrict__ Wrel,
    ushort_t* __restrict__ rel)
{
  int gid = blockIdx.x*256 + threadIdx.x;
  if (gid >= NPOS*HID) return;
  int p = gid >> 10, n = gid & 1023;
  const float* a = pe + p*HID;
  const float* w = Wrel + (size_t)n*HID;
  float s = 0.f;
  for (int k=0;k<HID;k+=4){
    float4v av = *(const float4v*)(a+k);
    float4v wv = *(const float4v*)(w+k);
#pragma unroll
    for (int u=0;u<4;u++) s += av[u]*wv[u];
  }
  rel[gid] = f2bf(s);
}

// MFMA attention on fused qkv[row][3072] (q:0, k:+1024, v:+2048).
// block = 4 waves = 4 consecutive chunks of one (b,h).
__global__ __launch_bounds__(256) void attn_kernel(
  const ushort_t* __restrict__ qkv, const ushort_t* __restrict__ rel,
  ushort_t* __restrict__ o, int S)
{
  const int n0 = blockIdx.x * 4;
  const int b  = blockIdx.y, h = blockIdx.z;
  const int tid = threadIdx.x;
  const size_t bS = (size_t)b * S;

  __shared__ ushort_t ks[68][136];
  __shared__ ushort_t vt[128][68];
  __shared__ ushort_t rs[32][136];
  __shared__ float    sA[4][12][36];
  __shared__ float    sB[4][12][36];
  __shared__ ushort_t Pp[4][16][40];

  const int base = n0*CHUNK - PAST;
  {
    const int r0 = tid >> 4;
    const int c0 = (tid & 15) * 8;
    for (int r = r0; r < 68; r += 16){
      int s = base + r;
      short8 kv = (short8)0, vv = (short8)0;
      if (r < 60 && s >= 0 && s < S){
        kv = *(const short8*)&qkv[(bS + s)*QKVW + 1024 + h*DH + c0];
        vv = *(const short8*)&qkv[(bS + s)*QKVW + 2048 + h*DH + c0];
      }
      *(short8*)&ks[r][c0] = kv;
#pragma unroll
      for (int u=0;u<8;u++) vt[c0+u][r] = (ushort_t)vv[u];
    }
    for (int r = r0; r < 32; r += 16){
      short8 rv = (short8)0;
      if (r < NPOS) rv = *(const short8*)&rel[r*HID + h*DH + c0];
      *(short8*)&rs[r][c0] = rv;
    }
  }
  __syncthreads();

  const int w    = tid >> 6;
  const int lane = tid & 63;
  const int lr   = lane & 15;
  const int lg   = lane >> 4;

  int qrow = (n0 + w)*CHUNK + lr;
  if (qrow >= S) qrow = S - 1;
  const ushort_t* qp = qkv + (bS + qrow)*QKVW + h*DH + lg*8;
  short8 qf[4];
#pragma unroll
  for (int ks2=0; ks2<4; ks2++) qf[ks2] = *(const short8*)(qp + ks2*32);

  // AC = q @ k^T
#pragma unroll
  for (int t0=0; t0<2; t0++){
    float4v acc = (float4v)0.0f;
#pragma unroll
    for (int ks2=0; ks2<4; ks2++){
      short8 kf = *(const short8*)&ks[w*CHUNK + t0*16 + lr][ks2*32 + lg*8];
      acc = __builtin_amdgcn_mfma_f32_16x16x32_bf16(qf[ks2], kf, acc, 0,0,0);
    }
#pragma unroll
    for (int reg=0; reg<4; reg++){
      int cr = lg*4 + reg;
      if (cr < CHUNK) sA[w][cr][t0*16 + lr] = acc[reg];
    }
  }

  // BD = q @ rel^T
#pragma unroll
  for (int t0=0; t0<2; t0++){
    float4v acc = (float4v)0.0f;
#pragma unroll
    for (int ks2=0; ks2<4; ks2++){
      short8 rf = *(const short8*)&rs[t0*16 + lr][ks2*32 + lg*8];
      acc = __builtin_amdgcn_mfma_f32_16x16x32_bf16(qf[ks2], rf, acc, 0,0,0);
    }
#pragma unroll
    for (int reg=0; reg<4; reg++){
      int cr = lg*4 + reg;
      if (cr < CHUNK) sB[w][cr][t0*16 + lr] = acc[reg];
    }
  }

#pragma unroll
  for (int i=0;i<2;i++){
    int idx = i*64 + lane;
    *(s4v*)&Pp[w][idx>>3][(idx&7)*4] = (s4v)0;
  }

  // rel-shift + softcap + softmax (wave-parallel)
  {
    const int c2 = lane >> 5;
    const int t  = lane & 31;
#pragma unroll
    for (int i=0;i<6;i++){
      int c = i*2 + c2;
      float x = -1e30f;
      if (t < CTX){
        int f = c*CTX + t;
        int r = f / NPOS, p = f - r*NPOS;
        x = sA[w][c][t] + sB[w][r][p];
        x = 50.0f * tanhf(x * 0.02f);
      }
      float m = x;
      for (int off=16; off>=1; off>>=1) m = fmaxf(m, __shfl_xor(m, off, 32));
      float e = (t < CTX) ? expf(x - m) : 0.0f;
      float s = e;
      for (int off=16; off>=1; off>>=1) s += __shfl_xor(s, off, 32);
      if (t < CTX) Pp[w][c][t] = f2bf(e / s);
    }
  }

  // PV: O[12x128] = P @ V
  short8 pf = *(const short8*)&Pp[w][lr][lg*8];
  const int orow_base = (n0 + w)*CHUNK;
#pragma unroll
  for (int j=0; j<8; j++){
    int d  = j*16 + lr;
    int tb = w*CHUNK + lg*8;
    s4v b0 = *(const s4v*)&vt[d][tb];
    s4v b1 = *(const s4v*)&vt[d][tb+4];
    short8 bf;
#pragma unroll
    for (int u=0;u<4;u++){ bf[u] = b0[u]; bf[u+4] = b1[u]; }
    float4v a = __builtin_amdgcn_mfma_f32_16x16x32_bf16(pf, bf, (float4v)0.0f, 0,0,0);
#pragma unroll
    for (int reg=0; reg<4; reg++){
      int cr = lg*4 + reg;
      if (cr < CHUNK)
        o[(bS + orow_base + cr)*HID + h*DH + j*16 + lr] = f2bf(a[reg]);
    }
  }
}

extern "C" void kernel_launch(void* const* d_in, const int* in_sizes, int n_in,
                              void* d_out, int out_size, void* d_ws, size_t ws_size,
                              hipStream_t stream)
{
  const float* hs    = (const float*)d_in[0];
  const float* pe    = (const float*)d_in[1];
  const float* Wq    = (const float*)d_in[2];
  const float* Wk    = (const float*)d_in[3];
  const float* Wv    = (const float*)d_in[4];
  const float* Wpost = (const float*)d_in[5];
  const float* Wrel  = (const float*)d_in[6];
  const float* pds   = (const float*)d_in[7];
  float* out = (float*)d_out;

  const int BS = in_sizes[0] / HID;   // 24576
  const int B  = 4;
  const int S  = BS / B;              // 6144
  const int nb = S / CHUNK;           // 512

  const size_t per = (size_t)BS * HID;
  const size_t wsz = (size_t)HID * HID;
  ushort_t* qkv  = (ushort_t*)d_ws;            // BS * 3072
  ushort_t* at   = qkv  + (size_t)BS * QKVW;   // BS * 1024
  ushort_t* rel  = at   + per;                 // 25 * 1024
  ushort_t* hsb  = rel  + (size_t)NPOS*HID;    // BS * 1024
  ushort_t* Wcat = hsb  + per;                 // 3072 * 1024 (Wq|Wk|Wv rows)
  ushort_t* Wpb  = Wcat + 3*wsz;               // 1024 * 1024

  const float qsc = (float)(pow((double)DH, -0.5) / log(2.0));   // D^-0.5/ln2
  const float ksc = (float)(log(1.0 + exp(1.0)) / log(2.0));     // ln(1+e)/ln2

  cvt_f2b<<<2048, 256, 0, stream>>>(hs,    hsb,          (int)(per/4));
  cvt_f2b<<<1024, 256, 0, stream>>>(Wq,    Wcat,         (int)(wsz/4));
  cvt_f2b<<<1024, 256, 0, stream>>>(Wk,    Wcat + wsz,   (int)(wsz/4));
  cvt_f2b<<<1024, 256, 0, stream>>>(Wv,    Wcat + 2*wsz, (int)(wsz/4));
  cvt_f2b<<<1024, 256, 0, stream>>>(Wpost, Wpb,          (int)(wsz/4));

  // fused QKV projection: [24576,1024] @ [3072,1024]^T -> qkv[24576,3072]
  gemm_lds<1,0><<<dim3(BS/128, QKVW/128), 256, 0, stream>>>(
      hsb, Wcat, qkv, BS, QKVW, HID, pds, qsc, ksc);
  relk_kernel<<<(NPOS*HID + 255)/256, 256, 0, stream>>>(pe, Wrel, rel);
  attn_kernel<<<dim3(nb/4, B, NH), 256, 0, stream>>>(qkv, rel, at, S);
  // output projection: [24576,1024] @ [1024,1024]^T -> out (f32)
  gemm_lds<0,1><<<dim3(BS/128, HID/128), 256, 0, stream>>>(
      at, Wpb, out, BS, HID, HID, nullptr, 1.0f, 1.0f);
}

// Round 5
// 441.483 us; speedup vs baseline: 1.7620x; 1.0846x over previous
//
#include <hip/hip_runtime.h>
#include <hip/hip_bf16.h>
#include <math.h>

typedef unsigned short ushort_t;
typedef __attribute__((ext_vector_type(8))) short short8;
typedef __attribute__((ext_vector_type(4))) short s4v;
typedef __attribute__((ext_vector_type(4))) float float4v;

#define HID 1024
#define NH 8
#define DH 128
#define CHUNK 12
#define PAST 12
#define CTX 24
#define NPOS 25
#define QKVW 3072

__device__ __forceinline__ float bf2f(ushort_t b){
  union{unsigned int u; float f;} x; x.u = ((unsigned int)b)<<16; return x.f;
}
__device__ __forceinline__ ushort_t f2bf(float f){
  union{float f; unsigned int u;} x; x.f = f;
  unsigned int u = x.u;
  unsigned int r = u + 0x7fffu + ((u>>16)&1u);
  return (ushort_t)(r>>16);
}

// async global->LDS, 16B per lane; LDS dest = wave-uniform base + lane*16
__device__ __forceinline__ void gload16(const ushort_t* g, ushort_t* l){
  __builtin_amdgcn_global_load_lds(
      (const __attribute__((address_space(1))) unsigned int*)g,
      (__attribute__((address_space(3))) unsigned int*)l,
      16, 0, 0);
}

// f32 -> bf16 conversion, vectorized, grid-stride (n4 = elems/4)
__global__ __launch_bounds__(256) void cvt_f2b(
    const float* __restrict__ in, ushort_t* __restrict__ out, int n4)
{
  for (int i = blockIdx.x*256 + threadIdx.x; i < n4; i += gridDim.x*256){
    float4v v = ((const float4v*)in)[i];
    s4v o;
#pragma unroll
    for (int j=0;j<4;j++) o[j] = (short)f2bf(v[j]);
    ((s4v*)out)[i] = o;
  }
}

// C[M,N] = A[M,K] @ W[N,K]^T  (bf16 in, f32 accum)
// 128x128 tile, BK=32, double-buffered linear LDS, global_load_lds staging,
// 1 barrier per K-step (T3 minimal 2-phase), 1D grid: n-tile fastest,
// XCD-chunked bijective block swizzle.
// MODE: 0 = no scale, 1 = fused qkv epilogue. OUTF: 0 = bf16 out, 1 = f32 out
template<int MODE, int OUTF>
__global__ __launch_bounds__(256) void gemm2(
    const ushort_t* __restrict__ A, const ushort_t* __restrict__ W,
    void* __restrict__ Cv, int M, int N, int K,
    const float* __restrict__ pds, float qsc, float ksc)
{
  // ---- bijective XCD-chunked swizzle (m204) ----
  const int nwg  = gridDim.x;
  const int orig = blockIdx.x;
  const int qch  = nwg >> 3, rch = nwg & 7;
  const int xcd  = orig & 7, idx = orig >> 3;
  const int bid  = (xcd < rch ? xcd*(qch+1) : rch*(qch+1) + (xcd-rch)*qch) + idx;

  const int NT = N >> 7;                 // n-tiles (fastest)
  const int m0 = (bid / NT) * 128;
  const int n0 = (bid % NT) * 128;

  const int tid  = threadIdx.x;
  const int w    = tid >> 6, lane = tid & 63;
  const int wm   = w >> 1, wn = w & 1;
  const int lr   = lane & 15;
  const int lg   = lane >> 4;

  __shared__ ushort_t As0[128*32], Bs0[128*32];
  __shared__ ushort_t As1[128*32], Bs1[128*32];

  float4v acc[4][4];
#pragma unroll
  for (int i=0;i<4;i++)
#pragma unroll
    for (int j=0;j<4;j++) acc[i][j] = (float4v)0.0f;

  const int sr = lane >> 2;        // 0..15
  const int sc = (lane & 3) * 8;   // 4 lanes cover one 64B row

  const ushort_t* Ab0 = A + (size_t)(m0 + w*16      + sr)*K + sc;
  const ushort_t* Ab1 = A + (size_t)(m0 + 64 + w*16 + sr)*K + sc;
  const ushort_t* Bb0 = W + (size_t)(n0 + w*16      + sr)*K + sc;
  const ushort_t* Bb1 = W + (size_t)(n0 + 64 + w*16 + sr)*K + sc;
  ushort_t* la0;  ushort_t* lb0;  ushort_t* la1;  ushort_t* lb1;

#define STAGE(Abuf, Bbuf, kt) do {                    \
    gload16(Ab0 + (kt), &(Abuf)[(w*16)*32]);          \
    gload16(Ab1 + (kt), &(Abuf)[(64 + w*16)*32]);     \
    gload16(Bb0 + (kt), &(Bbuf)[(w*16)*32]);          \
    gload16(Bb1 + (kt), &(Bbuf)[(64 + w*16)*32]);     \
  } while(0)

#define COMPUTE(Abuf, Bbuf) do {                                             \
    short8 afr[4], bfr[4];                                                   \
    _Pragma("unroll")                                                        \
    for (int i=0;i<4;i++) afr[i] = *(const short8*)&(Abuf)[(wm*64 + i*16 + lr)*32 + lg*8]; \
    _Pragma("unroll")                                                        \
    for (int j=0;j<4;j++) bfr[j] = *(const short8*)&(Bbuf)[(wn*64 + j*16 + lr)*32 + lg*8]; \
    _Pragma("unroll")                                                        \
    for (int i=0;i<4;i++)                                                    \
      _Pragma("unroll")                                                      \
      for (int j=0;j<4;j++)                                                  \
        acc[i][j] = __builtin_amdgcn_mfma_f32_16x16x32_bf16(afr[i], bfr[j], acc[i][j], 0,0,0); \
  } while(0)

  const int nt = K >> 5;           // K-steps (32 for K=1024), even
  STAGE(As0, Bs0, 0);
  __syncthreads();                 // buf0 staged (vmcnt drain in barrier)

  for (int t = 0; t < nt; t += 2){
    if (t+1 < nt) STAGE(As1, Bs1, (t+1)*32);
    COMPUTE(As0, Bs0);
    __syncthreads();               // buf1 staged; all reads of buf0 done
    if (t+2 < nt) STAGE(As0, Bs0, (t+2)*32);
    COMPUTE(As1, Bs1);
    __syncthreads();               // buf0 staged; all reads of buf1 done
  }
#undef STAGE
#undef COMPUTE

#pragma unroll
  for (int j=0;j<4;j++){
    int col = n0 + wn*64 + j*16 + lr;
    float scale = 1.0f;
    if (MODE==1){
      if (col < 1024){ float p = pds[col & (DH-1)]; scale = qsc * log1pf(expf(p)); }
      else if (col < 2048) scale = ksc;
    }
#pragma unroll
    for (int i=0;i<4;i++){
      int row = m0 + wm*64 + i*16 + lg*4;
#pragma unroll
      for (int r=0;r<4;r++){
        float val = acc[i][j][r] * scale;
        if (OUTF) ((float*)Cv)[(size_t)(row + r)*N + col] = val;
        else ((ushort_t*)Cv)[(size_t)(row + r)*N + col] = f2bf(val);
      }
    }
  }
}

// rel[25,1024] = pos_emb[25,1024] @ Wrel[1024,1024]^T   (f32 in, bf16 out)
__global__ __launch_bounds__(256) void relk_kernel(
    const float* __restrict__ pe, const float* __restrict__ Wrel,
    ushort_t* __restrict__ rel)
{
  int gid = blockIdx.x*256 + threadIdx.x;
  if (gid >= NPOS*HID) return;
  int p = gid >> 10, n = gid & 1023;
  const float* a = pe + p*HID;
  const float* w = Wrel + (size_t)n*HID;
  float s = 0.f;
  for (int k=0;k<HID;k+=4){
    float4v av = *(const float4v*)(a+k);
    float4v wv = *(const float4v*)(w+k);
#pragma unroll
    for (int u=0;u<4;u++) s += av[u]*wv[u];
  }
  rel[gid] = f2bf(s);
}

// MFMA attention on fused qkv[row][3072] (q:0, k:+1024, v:+2048).
// block = 4 waves = 4 consecutive chunks of one (b,h).
__global__ __launch_bounds__(256) void attn_kernel(
  const ushort_t* __restrict__ qkv, const ushort_t* __restrict__ rel,
  ushort_t* __restrict__ o, int S)
{
  const int n0 = blockIdx.x * 4;
  const int b  = blockIdx.y, h = blockIdx.z;
  const int tid = threadIdx.x;
  const size_t bS = (size_t)b * S;

  __shared__ ushort_t ks[68][136];
  __shared__ ushort_t vt[128][68];
  __shared__ ushort_t rs[32][136];
  __shared__ float    sA[4][12][36];
  __shared__ float    sB[4][12][36];
  __shared__ ushort_t Pp[4][16][40];

  const int base = n0*CHUNK - PAST;
  {
    const int r0 = tid >> 4;
    const int c0 = (tid & 15) * 8;
    for (int r = r0; r < 68; r += 16){
      int s = base + r;
      short8 kv = (short8)0, vv = (short8)0;
      if (r < 60 && s >= 0 && s < S){
        kv = *(const short8*)&qkv[(bS + s)*QKVW + 1024 + h*DH + c0];
        vv = *(const short8*)&qkv[(bS + s)*QKVW + 2048 + h*DH + c0];
      }
      *(short8*)&ks[r][c0] = kv;
#pragma unroll
      for (int u=0;u<8;u++) vt[c0+u][r] = (ushort_t)vv[u];
    }
    for (int r = r0; r < 32; r += 16){
      short8 rv = (short8)0;
      if (r < NPOS) rv = *(const short8*)&rel[r*HID + h*DH + c0];
      *(short8*)&rs[r][c0] = rv;
    }
  }
  __syncthreads();

  const int w    = tid >> 6;
  const int lane = tid & 63;
  const int lr   = lane & 15;
  const int lg   = lane >> 4;

  int qrow = (n0 + w)*CHUNK + lr;
  if (qrow >= S) qrow = S - 1;
  const ushort_t* qp = qkv + (bS + qrow)*QKVW + h*DH + lg*8;
  short8 qf[4];
#pragma unroll
  for (int ks2=0; ks2<4; ks2++) qf[ks2] = *(const short8*)(qp + ks2*32);

  // AC = q @ k^T
#pragma unroll
  for (int t0=0; t0<2; t0++){
    float4v acc = (float4v)0.0f;
#pragma unroll
    for (int ks2=0; ks2<4; ks2++){
      short8 kf = *(const short8*)&ks[w*CHUNK + t0*16 + lr][ks2*32 + lg*8];
      acc = __builtin_amdgcn_mfma_f32_16x16x32_bf16(qf[ks2], kf, acc, 0,0,0);
    }
#pragma unroll
    for (int reg=0; reg<4; reg++){
      int cr = lg*4 + reg;
      if (cr < CHUNK) sA[w][cr][t0*16 + lr] = acc[reg];
    }
  }

  // BD = q @ rel^T
#pragma unroll
  for (int t0=0; t0<2; t0++){
    float4v acc = (float4v)0.0f;
#pragma unroll
    for (int ks2=0; ks2<4; ks2++){
      short8 rf = *(const short8*)&rs[t0*16 + lr][ks2*32 + lg*8];
      acc = __builtin_amdgcn_mfma_f32_16x16x32_bf16(qf[ks2], rf, acc, 0,0,0);
    }
#pragma unroll
    for (int reg=0; reg<4; reg++){
      int cr = lg*4 + reg;
      if (cr < CHUNK) sB[w][cr][t0*16 + lr] = acc[reg];
    }
  }

#pragma unroll
  for (int i=0;i<2;i++){
    int idx = i*64 + lane;
    *(s4v*)&Pp[w][idx>>3][(idx&7)*4] = (s4v)0;
  }

  // rel-shift + softcap + softmax (wave-parallel)
  {
    const int c2 = lane >> 5;
    const int t  = lane & 31;
#pragma unroll
    for (int i=0;i<6;i++){
      int c = i*2 + c2;
      float x = -1e30f;
      if (t < CTX){
        int f = c*CTX + t;
        int r = f / NPOS, p = f - r*NPOS;
        x = sA[w][c][t] + sB[w][r][p];
        x = 50.0f * tanhf(x * 0.02f);
      }
      float m = x;
      for (int off=16; off>=1; off>>=1) m = fmaxf(m, __shfl_xor(m, off, 32));
      float e = (t < CTX) ? expf(x - m) : 0.0f;
      float s = e;
      for (int off=16; off>=1; off>>=1) s += __shfl_xor(s, off, 32);
      if (t < CTX) Pp[w][c][t] = f2bf(e / s);
    }
  }

  // PV: O[12x128] = P @ V
  short8 pf = *(const short8*)&Pp[w][lr][lg*8];
  const int orow_base = (n0 + w)*CHUNK;
#pragma unroll
  for (int j=0; j<8; j++){
    int d  = j*16 + lr;
    int tb = w*CHUNK + lg*8;
    s4v b0 = *(const s4v*)&vt[d][tb];
    s4v b1 = *(const s4v*)&vt[d][tb+4];
    short8 bf;
#pragma unroll
    for (int u=0;u<4;u++){ bf[u] = b0[u]; bf[u+4] = b1[u]; }
    float4v a = __builtin_amdgcn_mfma_f32_16x16x32_bf16(pf, bf, (float4v)0.0f, 0,0,0);
#pragma unroll
    for (int reg=0; reg<4; reg++){
      int cr = lg*4 + reg;
      if (cr < CHUNK)
        o[(bS + orow_base + cr)*HID + h*DH + j*16 + lr] = f2bf(a[reg]);
    }
  }
}

extern "C" void kernel_launch(void* const* d_in, const int* in_sizes, int n_in,
                              void* d_out, int out_size, void* d_ws, size_t ws_size,
                              hipStream_t stream)
{
  const float* hs    = (const float*)d_in[0];
  const float* pe    = (const float*)d_in[1];
  const float* Wq    = (const float*)d_in[2];
  const float* Wk    = (const float*)d_in[3];
  const float* Wv    = (const float*)d_in[4];
  const float* Wpost = (const float*)d_in[5];
  const float* Wrel  = (const float*)d_in[6];
  const float* pds   = (const float*)d_in[7];
  float* out = (float*)d_out;

  const int BS = in_sizes[0] / HID;   // 24576
  const int B  = 4;
  const int S  = BS / B;              // 6144
  const int nb = S / CHUNK;           // 512

  const size_t per = (size_t)BS * HID;
  const size_t wsz = (size_t)HID * HID;
  ushort_t* qkv  = (ushort_t*)d_ws;            // BS * 3072
  ushort_t* at   = qkv  + (size_t)BS * QKVW;   // BS * 1024
  ushort_t* rel  = at   + per;                 // 25 * 1024
  ushort_t* hsb  = rel  + (size_t)NPOS*HID;    // BS * 1024
  ushort_t* Wcat = hsb  + per;                 // 3072 * 1024 (Wq|Wk|Wv rows)
  ushort_t* Wpb  = Wcat + 3*wsz;               // 1024 * 1024

  const float qsc = (float)(pow((double)DH, -0.5) / log(2.0));   // D^-0.5/ln2
  const float ksc = (float)(log(1.0 + exp(1.0)) / log(2.0));     // ln(1+e)/ln2

  cvt_f2b<<<2048, 256, 0, stream>>>(hs,    hsb,          (int)(per/4));
  cvt_f2b<<<1024, 256, 0, stream>>>(Wq,    Wcat,         (int)(wsz/4));
  cvt_f2b<<<1024, 256, 0, stream>>>(Wk,    Wcat + wsz,   (int)(wsz/4));
  cvt_f2b<<<1024, 256, 0, stream>>>(Wv,    Wcat + 2*wsz, (int)(wsz/4));
  cvt_f2b<<<1024, 256, 0, stream>>>(Wpost, Wpb,          (int)(wsz/4));

  // fused QKV projection: [24576,1024] @ [3072,1024]^T -> qkv[24576,3072]
  gemm2<1,0><<<(BS/128)*(QKVW/128), 256, 0, stream>>>(
      hsb, Wcat, qkv, BS, QKVW, HID, pds, qsc, ksc);
  relk_kernel<<<(NPOS*HID + 255)/256, 256, 0, stream>>>(pe, Wrel, rel);
  attn_kernel<<<dim3(nb/4, B, NH), 256, 0, stream>>>(qkv, rel, at, S);
  // output projection: [24576,1024] @ [1024,1024]^T -> out (f32)
  gemm2<0,1><<<(BS/128)*(HID/128), 256, 0, stream>>>(
      at, Wpb, out, BS, HID, HID, nullptr, 1.0f, 1.0f);
}

// Round 6
// 441.087 us; speedup vs baseline: 1.7636x; 1.0009x over previous
//
#include <hip/hip_runtime.h>
#include <hip/hip_bf16.h>
#include <math.h>

typedef unsigned short ushort_t;
typedef __attribute__((ext_vector_type(8))) short short8;
typedef __attribute__((ext_vector_type(4))) short s4v;
typedef __attribute__((ext_vector_type(4))) float float4v;

#define HID 1024
#define NH 8
#define DH 128
#define CHUNK 12
#define PAST 12
#define CTX 24
#define NPOS 25
#define QKVW 3072

__device__ __forceinline__ float bf2f(ushort_t b){
  union{unsigned int u; float f;} x; x.u = ((unsigned int)b)<<16; return x.f;
}
__device__ __forceinline__ ushort_t f2bf(float f){
  union{float f; unsigned int u;} x; x.f = f;
  unsigned int u = x.u;
  unsigned int r = u + 0x7fffu + ((u>>16)&1u);
  return (ushort_t)(r>>16);
}

// async global->LDS, 16B per lane; LDS dest = wave-uniform base + lane*16
__device__ __forceinline__ void gload16(const ushort_t* g, ushort_t* l){
  __builtin_amdgcn_global_load_lds(
      (const __attribute__((address_space(1))) unsigned int*)g,
      (__attribute__((address_space(3))) unsigned int*)l,
      16, 0, 0);
}

// f32 -> bf16 conversion, vectorized, grid-stride (n4 = elems/4)
__global__ __launch_bounds__(256) void cvt_f2b(
    const float* __restrict__ in, ushort_t* __restrict__ out, int n4)
{
  for (int i = blockIdx.x*256 + threadIdx.x; i < n4; i += gridDim.x*256){
    float4v v = ((const float4v*)in)[i];
    s4v o;
#pragma unroll
    for (int j=0;j<4;j++) o[j] = (short)f2bf(v[j]);
    ((s4v*)out)[i] = o;
  }
}

// all 4 weights in one launch: Wq|Wk|Wv -> Wcat, Wpost -> Wpb (each wsz elems)
__global__ __launch_bounds__(256) void cvt_w4(
    const float* __restrict__ Wq, const float* __restrict__ Wk,
    const float* __restrict__ Wv, const float* __restrict__ Wp,
    ushort_t* __restrict__ Wcat, ushort_t* __restrict__ Wpb, int wsz4)
{
  for (int i = blockIdx.x*256 + threadIdx.x; i < 4*wsz4; i += gridDim.x*256){
    int seg = i / wsz4, off = i - seg*wsz4;
    const float* src = (seg==0) ? Wq : (seg==1) ? Wk : (seg==2) ? Wv : Wp;
    float4v v = ((const float4v*)src)[off];
    s4v o;
#pragma unroll
    for (int j=0;j<4;j++) o[j] = (short)f2bf(v[j]);
    if (seg < 3) ((s4v*)Wcat)[seg*wsz4 + off] = o;
    else         ((s4v*)Wpb)[off] = o;
  }
}

// ============ 256x256 BK=64 phase-split GEMM (T2+T5, 2-ring LDS) ============
// C[M,N] = A[M,K] @ W[N,K]^T. 512 thr = 8 waves (2m x 4n), per-wave out 128x64.
// LDS 128KB: lds[buf][A/B][256*64] bf16, XOR slot-swizzle (slot^=row&7) applied
// via inverse-swizzled global source (linear gload_lds dest) + swizzled ds_read.
// Depth-1 ring: stage t+1 into buf^1 during t's 4 phases; __syncthreads at tile
// boundary provides the exact vmcnt(0)+barrier needed. Per-phase raw s_barrier
// + setprio(1) around the 16-MFMA cluster (T5).
template<int MODE, int OUTF>
__global__ __launch_bounds__(512) void gemm8(
    const ushort_t* __restrict__ A, const ushort_t* __restrict__ W,
    void* __restrict__ Cv, int M, int N, int K,
    const float* __restrict__ pds, float qsc, float ksc)
{
  // bijective XCD-chunked swizzle (m204)
  const int nwg  = gridDim.x;
  const int orig = blockIdx.x;
  const int qch  = nwg >> 3, rch = nwg & 7;
  const int xcd  = orig & 7, idx = orig >> 3;
  const int bid  = (xcd < rch ? xcd*(qch+1) : rch*(qch+1) + (xcd-rch)*qch) + idx;

  const int NT = N >> 8;                 // 256-wide n-tiles, fastest
  const int m0 = (bid / NT) * 256;
  const int n0 = (bid % NT) * 256;

  const int tid  = threadIdx.x;
  const int w    = tid >> 6, lane = tid & 63;
  const int wm   = w >> 2, wn = w & 3;   // 2x4 waves
  const int lr   = lane & 15;
  const int lg   = lane >> 4;

  __shared__ ushort_t lds[2][2][256*64]; // 128 KB

  float4v acc[2][4][4];
#pragma unroll
  for (int mh=0; mh<2; mh++)
#pragma unroll
    for (int i=0;i<4;i++)
#pragma unroll
      for (int j=0;j<4;j++) acc[mh][i][j] = (float4v)0.0f;

  // staging geometry: one gload16 call/wave covers 8 rows x 64 elems (1KB)
  const int srow = lane >> 3;            // 0..7 row in group
  const int sg   = ((lane & 7) ^ srow) * 8;  // inverse-swizzled source slot

  const ushort_t* Ab = A + (size_t)m0 * K;
  const ushort_t* Wb = W + (size_t)n0 * K;

#define STAGE_C(c, buf, kt) do {                                              \
    const int rr_ = (c)*64 + w*8 + srow;                                      \
    gload16(Ab + (size_t)rr_*K + (kt) + sg, &lds[buf][0][((c)*64 + w*8)*64]); \
    gload16(Wb + (size_t)rr_*K + (kt) + sg, &lds[buf][1][((c)*64 + w*8)*64]); \
  } while(0)

  short8 bfr[4];

#define PHASE(buf, mh, kh, LOADB) do {                                        \
    short8 afr[4];                                                            \
    _Pragma("unroll")                                                         \
    for (int i=0;i<4;i++){                                                    \
      const int r_ = wm*128 + (mh)*64 + i*16 + lr;                            \
      const int s_ = (((kh)>>3) + lg) ^ (r_ & 7);                             \
      afr[i] = *(const short8*)&lds[buf][0][r_*64 + s_*8];                    \
    }                                                                         \
    if (LOADB){                                                               \
      _Pragma("unroll")                                                       \
      for (int j=0;j<4;j++){                                                  \
        const int r_ = wn*64 + j*16 + lr;                                     \
        const int s_ = (((kh)>>3) + lg) ^ (r_ & 7);                           \
        bfr[j] = *(const short8*)&lds[buf][1][r_*64 + s_*8];                  \
      }                                                                       \
    }                                                                         \
    __builtin_amdgcn_s_setprio(1);                                            \
    _Pragma("unroll")                                                         \
    for (int i=0;i<4;i++)                                                     \
      _Pragma("unroll")                                                       \
      for (int j=0;j<4;j++)                                                   \
        acc[mh][i][j] = __builtin_amdgcn_mfma_f32_16x16x32_bf16(              \
            afr[i], bfr[j], acc[mh][i][j], 0,0,0);                            \
    __builtin_amdgcn_s_setprio(0);                                            \
    __builtin_amdgcn_s_barrier();                                             \
  } while(0)

  const int NTiles = K >> 6;             // 16 for K=1024
  STAGE_C(0, 0, 0); STAGE_C(1, 0, 0); STAGE_C(2, 0, 0); STAGE_C(3, 0, 0);
  __syncthreads();

  for (int t = 0; t < NTiles; ++t){
    const int cur = t & 1, nxt = cur ^ 1;
    const int ktn = (t+1) << 6;
    const bool pf = (t+1 < NTiles);
    if (pf) STAGE_C(0, nxt, ktn);
    PHASE(cur, 0, 0, 1);
    if (pf) STAGE_C(1, nxt, ktn);
    PHASE(cur, 1, 0, 0);
    if (pf) STAGE_C(2, nxt, ktn);
    PHASE(cur, 0, 32, 1);
    if (pf) STAGE_C(3, nxt, ktn);
    PHASE(cur, 1, 32, 0);
    __syncthreads();                     // vmcnt(0)+lgkm(0)+barrier: t+1 ready
  }
#undef STAGE_C
#undef PHASE

#pragma unroll
  for (int j=0;j<4;j++){
    const int col = n0 + wn*64 + j*16 + lr;
    float scale = 1.0f;
    if (MODE==1){
      if (col < 1024){ float p = pds[col & (DH-1)]; scale = qsc * log1pf(expf(p)); }
      else if (col < 2048) scale = ksc;
    }
#pragma unroll
    for (int mh=0; mh<2; mh++)
#pragma unroll
      for (int i=0;i<4;i++){
        const int row = m0 + wm*128 + mh*64 + i*16 + lg*4;
#pragma unroll
        for (int r=0;r<4;r++){
          float val = acc[mh][i][j][r] * scale;
          if (OUTF) ((float*)Cv)[(size_t)(row + r)*N + col] = val;
          else ((ushort_t*)Cv)[(size_t)(row + r)*N + col] = f2bf(val);
        }
      }
  }
}

// ============ 128x128 BK=32 2-phase GEMM (for the output projection) ========
template<int MODE, int OUTF>
__global__ __launch_bounds__(256) void gemm2(
    const ushort_t* __restrict__ A, const ushort_t* __restrict__ W,
    void* __restrict__ Cv, int M, int N, int K,
    const float* __restrict__ pds, float qsc, float ksc)
{
  const int nwg  = gridDim.x;
  const int orig = blockIdx.x;
  const int qch  = nwg >> 3, rch = nwg & 7;
  const int xcd  = orig & 7, idx = orig >> 3;
  const int bid  = (xcd < rch ? xcd*(qch+1) : rch*(qch+1) + (xcd-rch)*qch) + idx;

  const int NT = N >> 7;
  const int m0 = (bid / NT) * 128;
  const int n0 = (bid % NT) * 128;

  const int tid  = threadIdx.x;
  const int w    = tid >> 6, lane = tid & 63;
  const int wm   = w >> 1, wn = w & 1;
  const int lr   = lane & 15;
  const int lg   = lane >> 4;

  __shared__ ushort_t As0[128*32], Bs0[128*32];
  __shared__ ushort_t As1[128*32], Bs1[128*32];

  float4v acc[4][4];
#pragma unroll
  for (int i=0;i<4;i++)
#pragma unroll
    for (int j=0;j<4;j++) acc[i][j] = (float4v)0.0f;

  const int sr = lane >> 2;
  const int sc = (lane & 3) * 8;

  const ushort_t* Ab0 = A + (size_t)(m0 + w*16      + sr)*K + sc;
  const ushort_t* Ab1 = A + (size_t)(m0 + 64 + w*16 + sr)*K + sc;
  const ushort_t* Bb0 = W + (size_t)(n0 + w*16      + sr)*K + sc;
  const ushort_t* Bb1 = W + (size_t)(n0 + 64 + w*16 + sr)*K + sc;

#define STAGE(Abuf, Bbuf, kt) do {                    \
    gload16(Ab0 + (kt), &(Abuf)[(w*16)*32]);          \
    gload16(Ab1 + (kt), &(Abuf)[(64 + w*16)*32]);     \
    gload16(Bb0 + (kt), &(Bbuf)[(w*16)*32]);          \
    gload16(Bb1 + (kt), &(Bbuf)[(64 + w*16)*32]);     \
  } while(0)

#define COMPUTE(Abuf, Bbuf) do {                                             \
    short8 afr[4], bfr[4];                                                   \
    _Pragma("unroll")                                                        \
    for (int i=0;i<4;i++) afr[i] = *(const short8*)&(Abuf)[(wm*64 + i*16 + lr)*32 + lg*8]; \
    _Pragma("unroll")                                                        \
    for (int j=0;j<4;j++) bfr[j] = *(const short8*)&(Bbuf)[(wn*64 + j*16 + lr)*32 + lg*8]; \
    _Pragma("unroll")                                                        \
    for (int i=0;i<4;i++)                                                    \
      _Pragma("unroll")                                                      \
      for (int j=0;j<4;j++)                                                  \
        acc[i][j] = __builtin_amdgcn_mfma_f32_16x16x32_bf16(afr[i], bfr[j], acc[i][j], 0,0,0); \
  } while(0)

  const int nt = K >> 5;
  STAGE(As0, Bs0, 0);
  __syncthreads();

  for (int t = 0; t < nt; t += 2){
    if (t+1 < nt) STAGE(As1, Bs1, (t+1)*32);
    COMPUTE(As0, Bs0);
    __syncthreads();
    if (t+2 < nt) STAGE(As0, Bs0, (t+2)*32);
    COMPUTE(As1, Bs1);
    __syncthreads();
  }
#undef STAGE
#undef COMPUTE

#pragma unroll
  for (int j=0;j<4;j++){
    int col = n0 + wn*64 + j*16 + lr;
    float scale = 1.0f;
    if (MODE==1){
      if (col < 1024){ float p = pds[col & (DH-1)]; scale = qsc * log1pf(expf(p)); }
      else if (col < 2048) scale = ksc;
    }
#pragma unroll
    for (int i=0;i<4;i++){
      int row = m0 + wm*64 + i*16 + lg*4;
#pragma unroll
      for (int r=0;r<4;r++){
        float val = acc[i][j][r] * scale;
        if (OUTF) ((float*)Cv)[(size_t)(row + r)*N + col] = val;
        else ((ushort_t*)Cv)[(size_t)(row + r)*N + col] = f2bf(val);
      }
    }
  }
}

// rel[25,1024] = pos_emb[25,1024] @ Wrel[1024,1024]^T   (f32 in, bf16 out)
__global__ __launch_bounds__(256) void relk_kernel(
    const float* __restrict__ pe, const float* __restrict__ Wrel,
    ushort_t* __restrict__ rel)
{
  int gid = blockIdx.x*256 + threadIdx.x;
  if (gid >= NPOS*HID) return;
  int p = gid >> 10, n = gid & 1023;
  const float* a = pe + p*HID;
  const float* w = Wrel + (size_t)n*HID;
  float s = 0.f;
  for (int k=0;k<HID;k+=4){
    float4v av = *(const float4v*)(a+k);
    float4v wv = *(const float4v*)(w+k);
#pragma unroll
    for (int u=0;u<4;u++) s += av[u]*wv[u];
  }
  rel[gid] = f2bf(s);
}

// MFMA attention on fused qkv[row][3072] (q:0, k:+1024, v:+2048).
// block = 4 waves = 4 consecutive chunks of one (b,h).
__global__ __launch_bounds__(256) void attn_kernel(
  const ushort_t* __restrict__ qkv, const ushort_t* __restrict__ rel,
  ushort_t* __restrict__ o, int S)
{
  const int n0 = blockIdx.x * 4;
  const int b  = blockIdx.y, h = blockIdx.z;
  const int tid = threadIdx.x;
  const size_t bS = (size_t)b * S;

  __shared__ ushort_t ks[68][136];
  __shared__ ushort_t vt[128][68];
  __shared__ ushort_t rs[32][136];
  __shared__ float    sA[4][12][36];
  __shared__ float    sB[4][12][36];
  __shared__ ushort_t Pp[4][16][40];

  const int base = n0*CHUNK - PAST;
  {
    const int r0 = tid >> 4;
    const int c0 = (tid & 15) * 8;
    for (int r = r0; r < 68; r += 16){
      int s = base + r;
      short8 kv = (short8)0, vv = (short8)0;
      if (r < 60 && s >= 0 && s < S){
        kv = *(const short8*)&qkv[(bS + s)*QKVW + 1024 + h*DH + c0];
        vv = *(const short8*)&qkv[(bS + s)*QKVW + 2048 + h*DH + c0];
      }
      *(short8*)&ks[r][c0] = kv;
#pragma unroll
      for (int u=0;u<8;u++) vt[c0+u][r] = (ushort_t)vv[u];
    }
    for (int r = r0; r < 32; r += 16){
      short8 rv = (short8)0;
      if (r < NPOS) rv = *(const short8*)&rel[r*HID + h*DH + c0];
      *(short8*)&rs[r][c0] = rv;
    }
  }
  __syncthreads();

  const int w    = tid >> 6;
  const int lane = tid & 63;
  const int lr   = lane & 15;
  const int lg   = lane >> 4;

  int qrow = (n0 + w)*CHUNK + lr;
  if (qrow >= S) qrow = S - 1;
  const ushort_t* qp = qkv + (bS + qrow)*QKVW + h*DH + lg*8;
  short8 qf[4];
#pragma unroll
  for (int ks2=0; ks2<4; ks2++) qf[ks2] = *(const short8*)(qp + ks2*32);

  // AC = q @ k^T
#pragma unroll
  for (int t0=0; t0<2; t0++){
    float4v acc = (float4v)0.0f;
#pragma unroll
    for (int ks2=0; ks2<4; ks2++){
      short8 kf = *(const short8*)&ks[w*CHUNK + t0*16 + lr][ks2*32 + lg*8];
      acc = __builtin_amdgcn_mfma_f32_16x16x32_bf16(qf[ks2], kf, acc, 0,0,0);
    }
#pragma unroll
    for (int reg=0; reg<4; reg++){
      int cr = lg*4 + reg;
      if (cr < CHUNK) sA[w][cr][t0*16 + lr] = acc[reg];
    }
  }

  // BD = q @ rel^T
#pragma unroll
  for (int t0=0; t0<2; t0++){
    float4v acc = (float4v)0.0f;
#pragma unroll
    for (int ks2=0; ks2<4; ks2++){
      short8 rf = *(const short8*)&rs[t0*16 + lr][ks2*32 + lg*8];
      acc = __builtin_amdgcn_mfma_f32_16x16x32_bf16(qf[ks2], rf, acc, 0,0,0);
    }
#pragma unroll
    for (int reg=0; reg<4; reg++){
      int cr = lg*4 + reg;
      if (cr < CHUNK) sB[w][cr][t0*16 + lr] = acc[reg];
    }
  }

#pragma unroll
  for (int i=0;i<2;i++){
    int idx = i*64 + lane;
    *(s4v*)&Pp[w][idx>>3][(idx&7)*4] = (s4v)0;
  }

  // rel-shift + softcap + softmax (wave-parallel)
  {
    const int c2 = lane >> 5;
    const int t  = lane & 31;
#pragma unroll
    for (int i=0;i<6;i++){
      int c = i*2 + c2;
      float x = -1e30f;
      if (t < CTX){
        int f = c*CTX + t;
        int r = f / NPOS, p = f - r*NPOS;
        x = sA[w][c][t] + sB[w][r][p];
        x = 50.0f * tanhf(x * 0.02f);
      }
      float m = x;
      for (int off=16; off>=1; off>>=1) m = fmaxf(m, __shfl_xor(m, off, 32));
      float e = (t < CTX) ? expf(x - m) : 0.0f;
      float s = e;
      for (int off=16; off>=1; off>>=1) s += __shfl_xor(s, off, 32);
      if (t < CTX) Pp[w][c][t] = f2bf(e / s);
    }
  }

  // PV: O[12x128] = P @ V
  short8 pf = *(const short8*)&Pp[w][lr][lg*8];
  const int orow_base = (n0 + w)*CHUNK;
#pragma unroll
  for (int j=0; j<8; j++){
    int d  = j*16 + lr;
    int tb = w*CHUNK + lg*8;
    s4v b0 = *(const s4v*)&vt[d][tb];
    s4v b1 = *(const s4v*)&vt[d][tb+4];
    short8 bf;
#pragma unroll
    for (int u=0;u<4;u++){ bf[u] = b0[u]; bf[u+4] = b1[u]; }
    float4v a = __builtin_amdgcn_mfma_f32_16x16x32_bf16(pf, bf, (float4v)0.0f, 0,0,0);
#pragma unroll
    for (int reg=0; reg<4; reg++){
      int cr = lg*4 + reg;
      if (cr < CHUNK)
        o[(bS + orow_base + cr)*HID + h*DH + j*16 + lr] = f2bf(a[reg]);
    }
  }
}

extern "C" void kernel_launch(void* const* d_in, const int* in_sizes, int n_in,
                              void* d_out, int out_size, void* d_ws, size_t ws_size,
                              hipStream_t stream)
{
  const float* hs    = (const float*)d_in[0];
  const float* pe    = (const float*)d_in[1];
  const float* Wq    = (const float*)d_in[2];
  const float* Wk    = (const float*)d_in[3];
  const float* Wv    = (const float*)d_in[4];
  const float* Wpost = (const float*)d_in[5];
  const float* Wrel  = (const float*)d_in[6];
  const float* pds   = (const float*)d_in[7];
  float* out = (float*)d_out;

  const int BS = in_sizes[0] / HID;   // 24576
  const int B  = 4;
  const int S  = BS / B;              // 6144
  const int nb = S / CHUNK;           // 512

  const size_t per = (size_t)BS * HID;
  const size_t wsz = (size_t)HID * HID;
  ushort_t* qkv  = (ushort_t*)d_ws;            // BS * 3072
  ushort_t* at   = qkv  + (size_t)BS * QKVW;   // BS * 1024
  ushort_t* rel  = at   + per;                 // 25 * 1024
  ushort_t* hsb  = rel  + (size_t)NPOS*HID;    // BS * 1024
  ushort_t* Wcat = hsb  + per;                 // 3072 * 1024 (Wq|Wk|Wv rows)
  ushort_t* Wpb  = Wcat + 3*wsz;               // 1024 * 1024

  const float qsc = (float)(pow((double)DH, -0.5) / log(2.0));   // D^-0.5/ln2
  const float ksc = (float)(log(1.0 + exp(1.0)) / log(2.0));     // ln(1+e)/ln2

  cvt_f2b<<<2048, 256, 0, stream>>>(hs, hsb, (int)(per/4));
  cvt_w4<<<2048, 256, 0, stream>>>(Wq, Wk, Wv, Wpost, Wcat, Wpb, (int)(wsz/4));

  // fused QKV projection: [24576,1024] @ [3072,1024]^T -> qkv[24576,3072]
  gemm8<1,0><<<(BS/256)*(QKVW/256), 512, 0, stream>>>(
      hsb, Wcat, qkv, BS, QKVW, HID, pds, qsc, ksc);
  relk_kernel<<<(NPOS*HID + 255)/256, 256, 0, stream>>>(pe, Wrel, rel);
  attn_kernel<<<dim3(nb/4, B, NH), 256, 0, stream>>>(qkv, rel, at, S);
  // output projection: [24576,1024] @ [1024,1024]^T -> out (f32)
  gemm2<0,1><<<(BS/128)*(HID/128), 256, 0, stream>>>(
      at, Wpb, out, BS, HID, HID, nullptr, 1.0f, 1.0f);
}

// Round 7
// 440.090 us; speedup vs baseline: 1.7676x; 1.0023x over previous
//
#include <hip/hip_runtime.h>
#include <hip/hip_bf16.h>
#include <math.h>

typedef unsigned short ushort_t;
typedef __attribute__((ext_vector_type(8))) short short8;
typedef __attribute__((ext_vector_type(4))) short s4v;
typedef __attribute__((ext_vector_type(4))) float float4v;

#define HID 1024
#define NH 8
#define DH 128
#define CHUNK 12
#define PAST 12
#define CTX 24
#define NPOS 25
#define QKVW 3072

__device__ __forceinline__ float bf2f(ushort_t b){
  union{unsigned int u; float f;} x; x.u = ((unsigned int)b)<<16; return x.f;
}
__device__ __forceinline__ ushort_t f2bf(float f){
  union{float f; unsigned int u;} x; x.f = f;
  unsigned int u = x.u;
  unsigned int r = u + 0x7fffu + ((u>>16)&1u);
  return (ushort_t)(r>>16);
}

// async global->LDS, 16B per lane; LDS dest = wave-uniform base + lane*16
__device__ __forceinline__ void gload16(const ushort_t* g, ushort_t* l){
  __builtin_amdgcn_global_load_lds(
      (const __attribute__((address_space(1))) unsigned int*)g,
      (__attribute__((address_space(3))) unsigned int*)l,
      16, 0, 0);
}

// f32 -> bf16 conversion, vectorized, grid-stride (n4 = elems/4)
__global__ __launch_bounds__(256) void cvt_f2b(
    const float* __restrict__ in, ushort_t* __restrict__ out, int n4)
{
  for (int i = blockIdx.x*256 + threadIdx.x; i < n4; i += gridDim.x*256){
    float4v v = ((const float4v*)in)[i];
    s4v o;
#pragma unroll
    for (int j=0;j<4;j++) o[j] = (short)f2bf(v[j]);
    ((s4v*)out)[i] = o;
  }
}

// all 4 weights in one launch: Wq|Wk|Wv -> Wcat, Wpost -> Wpb (each wsz elems)
__global__ __launch_bounds__(256) void cvt_w4(
    const float* __restrict__ Wq, const float* __restrict__ Wk,
    const float* __restrict__ Wv, const float* __restrict__ Wp,
    ushort_t* __restrict__ Wcat, ushort_t* __restrict__ Wpb, int wsz4)
{
  for (int i = blockIdx.x*256 + threadIdx.x; i < 4*wsz4; i += gridDim.x*256){
    int seg = i / wsz4, off = i - seg*wsz4;
    const float* src = (seg==0) ? Wq : (seg==1) ? Wk : (seg==2) ? Wv : Wp;
    float4v v = ((const float4v*)src)[off];
    s4v o;
#pragma unroll
    for (int j=0;j<4;j++) o[j] = (short)f2bf(v[j]);
    if (seg < 3) ((s4v*)Wcat)[seg*wsz4 + off] = o;
    else         ((s4v*)Wpb)[off] = o;
  }
}

// ====== 256x256 K-sliced counted-vmcnt pipeline GEMM (T2+T4+T5) ======
// C[M,N] = A[M,K] @ W[N,K]^T. 512 thr = 8 waves (2m x 4n), wave out 128x64.
// Phase p = K-slice [32p,32p+32). LDS ring: 4 slots x (A[256x32]+B[256x32]).
// Per phase: vmcnt(8); barrier; stage slice p+3 (4 gload_lds/wave);
// 12 ds_read_b128 (XOR-swizzled); setprio(1); 32 MFMA; setprio(0).
// Depth-3 pipeline: vmcnt never below 8 in main loop (T4). Swizzle:
// LDS 16B-slot sigma = row*4 + (kslot ^ (row&3)); inverse applied at the
// per-lane global source (gload dest stays linear), same XOR on ds_read.
// Requires K % 128 == 0, K >= 256.
template<int MODE, int OUTF>
__global__ __launch_bounds__(512, 2) void gemm8v2(
    const ushort_t* __restrict__ A, const ushort_t* __restrict__ W,
    void* __restrict__ Cv, int M, int N, int K,
    const float* __restrict__ pds, float qsc, float ksc)
{
  // bijective XCD-chunked swizzle (m204)
  const int nwg  = gridDim.x;
  const int orig = blockIdx.x;
  const int qch  = nwg >> 3, rch = nwg & 7;
  const int xcd  = orig & 7, idx = orig >> 3;
  const int bid  = (xcd < rch ? xcd*(qch+1) : rch*(qch+1) + (xcd-rch)*qch) + idx;

  const int NT = N >> 8;                 // 256-wide n-tiles, fastest
  const int m0 = (bid / NT) * 256;
  const int n0 = (bid % NT) * 256;

  const int tid  = threadIdx.x;
  const int w    = tid >> 6, lane = tid & 63;
  const int wm   = w >> 2, wn = w & 3;   // 2x4 waves, wave output 128x64
  const int lr   = lane & 15;
  const int lg   = lane >> 4;
  const int kswz = (lg ^ (lr & 3)) * 8;  // lane-constant swizzled k-slot (elems)

  __shared__ ushort_t lds[4][2][256*32]; // 4 slots x {A,B} x 16KB = 128KB

  float4v acc[8][4];
#pragma unroll
  for (int i=0;i<8;i++)
#pragma unroll
    for (int j=0;j<4;j++) acc[i][j] = (float4v)0.0f;

  // staging source: lane l covers (rowin = l>>2, lds kslot = l&3);
  // global kslot = (l&3) ^ (rowin&3)  [inverse swizzle]
  const int rowin = lane >> 2;
  const int kg    = ((lane & 3) ^ (rowin & 3)) * 8;
  const ushort_t* A0 = A + (size_t)(m0 + w*16 + rowin)*K + kg;
  const ushort_t* A1 = A0 + (size_t)128*K;
  const ushort_t* B0 = W + (size_t)(n0 + w*16 + rowin)*K + kg;
  const ushort_t* B1 = B0 + (size_t)128*K;

#define STAGEP(slot, ko) do {                              \
    gload16(A0 + (ko), &lds[slot][0][(w*16)*32]);          \
    gload16(A1 + (ko), &lds[slot][0][(128 + w*16)*32]);    \
    gload16(B0 + (ko), &lds[slot][1][(w*16)*32]);          \
    gload16(B1 + (ko), &lds[slot][1][(128 + w*16)*32]);    \
  } while(0)

#define PH(i, DOSTAGE, VM) do {                                              \
    asm volatile("s_waitcnt vmcnt(" #VM ")" ::: "memory");                   \
    __builtin_amdgcn_s_barrier();                                            \
    __builtin_amdgcn_sched_barrier(0);                                       \
    if (DOSTAGE){ STAGEP((((i)+3)&3), kn); kn += 32; }                       \
    short8 bfr[4];                                                           \
    _Pragma("unroll")                                                        \
    for (int j=0;j<4;j++)                                                    \
      bfr[j] = *(const short8*)&lds[i][1][(wn*64 + j*16 + lr)*32 + kswz];    \
    __builtin_amdgcn_s_setprio(1);                                           \
    _Pragma("unroll")                                                        \
    for (int ii=0; ii<8; ii++){                                              \
      short8 afr = *(const short8*)&lds[i][0][(wm*128 + ii*16 + lr)*32 + kswz]; \
      _Pragma("unroll")                                                      \
      for (int j=0;j<4;j++)                                                  \
        acc[ii][j] = __builtin_amdgcn_mfma_f32_16x16x32_bf16(                \
            afr, bfr[j], acc[ii][j], 0,0,0);                                 \
    }                                                                        \
    __builtin_amdgcn_s_setprio(0);                                           \
    __builtin_amdgcn_sched_barrier(0);                                       \
  } while(0)

  const int T = K >> 5;                  // phases (32 for K=1024), mult of 4
  STAGEP(0, 0); STAGEP(1, 32); STAGEP(2, 64);
  int kn = 96;

  for (int pb = 0; pb <= T - 8; pb += 4){
    PH(0,1,8); PH(1,1,8); PH(2,1,8); PH(3,1,8);
  }
  // tail: phases T-4..T-1
  PH(0,1,8); PH(1,0,8); PH(2,0,4); PH(3,0,0);
#undef STAGEP
#undef PH

#pragma unroll
  for (int j=0;j<4;j++){
    const int col = n0 + wn*64 + j*16 + lr;
    float scale = 1.0f;
    if (MODE==1){
      if (col < 1024){ float p = pds[col & (DH-1)]; scale = qsc * log1pf(expf(p)); }
      else if (col < 2048) scale = ksc;
    }
#pragma unroll
    for (int i=0;i<8;i++){
      const int row = m0 + wm*128 + i*16 + lg*4;
#pragma unroll
      for (int r=0;r<4;r++){
        float val = acc[i][j][r] * scale;
        if (OUTF) ((float*)Cv)[(size_t)(row + r)*N + col] = val;
        else ((ushort_t*)Cv)[(size_t)(row + r)*N + col] = f2bf(val);
      }
    }
  }
}

// ============ 128x128 BK=32 2-phase GEMM (for the output projection) ========
template<int MODE, int OUTF>
__global__ __launch_bounds__(256) void gemm2(
    const ushort_t* __restrict__ A, const ushort_t* __restrict__ W,
    void* __restrict__ Cv, int M, int N, int K,
    const float* __restrict__ pds, float qsc, float ksc)
{
  const int nwg  = gridDim.x;
  const int orig = blockIdx.x;
  const int qch  = nwg >> 3, rch = nwg & 7;
  const int xcd  = orig & 7, idx = orig >> 3;
  const int bid  = (xcd < rch ? xcd*(qch+1) : rch*(qch+1) + (xcd-rch)*qch) + idx;

  const int NT = N >> 7;
  const int m0 = (bid / NT) * 128;
  const int n0 = (bid % NT) * 128;

  const int tid  = threadIdx.x;
  const int w    = tid >> 6, lane = tid & 63;
  const int wm   = w >> 1, wn = w & 1;
  const int lr   = lane & 15;
  const int lg   = lane >> 4;

  __shared__ ushort_t As0[128*32], Bs0[128*32];
  __shared__ ushort_t As1[128*32], Bs1[128*32];

  float4v acc[4][4];
#pragma unroll
  for (int i=0;i<4;i++)
#pragma unroll
    for (int j=0;j<4;j++) acc[i][j] = (float4v)0.0f;

  const int sr = lane >> 2;
  const int sc = (lane & 3) * 8;

  const ushort_t* Ab0 = A + (size_t)(m0 + w*16      + sr)*K + sc;
  const ushort_t* Ab1 = A + (size_t)(m0 + 64 + w*16 + sr)*K + sc;
  const ushort_t* Bb0 = W + (size_t)(n0 + w*16      + sr)*K + sc;
  const ushort_t* Bb1 = W + (size_t)(n0 + 64 + w*16 + sr)*K + sc;

#define STAGE(Abuf, Bbuf, kt) do {                    \
    gload16(Ab0 + (kt), &(Abuf)[(w*16)*32]);          \
    gload16(Ab1 + (kt), &(Abuf)[(64 + w*16)*32]);     \
    gload16(Bb0 + (kt), &(Bbuf)[(w*16)*32]);          \
    gload16(Bb1 + (kt), &(Bbuf)[(64 + w*16)*32]);     \
  } while(0)

#define COMPUTE(Abuf, Bbuf) do {                                             \
    short8 afr[4], bfr[4];                                                   \
    _Pragma("unroll")                                                        \
    for (int i=0;i<4;i++) afr[i] = *(const short8*)&(Abuf)[(wm*64 + i*16 + lr)*32 + lg*8]; \
    _Pragma("unroll")                                                        \
    for (int j=0;j<4;j++) bfr[j] = *(const short8*)&(Bbuf)[(wn*64 + j*16 + lr)*32 + lg*8]; \
    _Pragma("unroll")                                                        \
    for (int i=0;i<4;i++)                                                    \
      _Pragma("unroll")                                                      \
      for (int j=0;j<4;j++)                                                  \
        acc[i][j] = __builtin_amdgcn_mfma_f32_16x16x32_bf16(afr[i], bfr[j], acc[i][j], 0,0,0); \
  } while(0)

  const int nt = K >> 5;
  STAGE(As0, Bs0, 0);
  __syncthreads();

  for (int t = 0; t < nt; t += 2){
    if (t+1 < nt) STAGE(As1, Bs1, (t+1)*32);
    COMPUTE(As0, Bs0);
    __syncthreads();
    if (t+2 < nt) STAGE(As0, Bs0, (t+2)*32);
    COMPUTE(As1, Bs1);
    __syncthreads();
  }
#undef STAGE
#undef COMPUTE

#pragma unroll
  for (int j=0;j<4;j++){
    int col = n0 + wn*64 + j*16 + lr;
    float scale = 1.0f;
    if (MODE==1){
      if (col < 1024){ float p = pds[col & (DH-1)]; scale = qsc * log1pf(expf(p)); }
      else if (col < 2048) scale = ksc;
    }
#pragma unroll
    for (int i=0;i<4;i++){
      int row = m0 + wm*64 + i*16 + lg*4;
#pragma unroll
      for (int r=0;r<4;r++){
        float val = acc[i][j][r] * scale;
        if (OUTF) ((float*)Cv)[(size_t)(row + r)*N + col] = val;
        else ((ushort_t*)Cv)[(size_t)(row + r)*N + col] = f2bf(val);
      }
    }
  }
}

// rel[25,1024] = pos_emb[25,1024] @ Wrel[1024,1024]^T   (f32 in, bf16 out)
__global__ __launch_bounds__(256) void relk_kernel(
    const float* __restrict__ pe, const float* __restrict__ Wrel,
    ushort_t* __restrict__ rel)
{
  int gid = blockIdx.x*256 + threadIdx.x;
  if (gid >= NPOS*HID) return;
  int p = gid >> 10, n = gid & 1023;
  const float* a = pe + p*HID;
  const float* w = Wrel + (size_t)n*HID;
  float s = 0.f;
  for (int k=0;k<HID;k+=4){
    float4v av = *(const float4v*)(a+k);
    float4v wv = *(const float4v*)(w+k);
#pragma unroll
    for (int u=0;u<4;u++) s += av[u]*wv[u];
  }
  rel[gid] = f2bf(s);
}

// MFMA attention on fused qkv[row][3072] (q:0, k:+1024, v:+2048).
// block = 4 waves = 4 consecutive chunks of one (b,h).
__global__ __launch_bounds__(256) void attn_kernel(
  const ushort_t* __restrict__ qkv, const ushort_t* __restrict__ rel,
  ushort_t* __restrict__ o, int S)
{
  const int n0 = blockIdx.x * 4;
  const int b  = blockIdx.y, h = blockIdx.z;
  const int tid = threadIdx.x;
  const size_t bS = (size_t)b * S;

  __shared__ ushort_t ks[68][136];
  __shared__ ushort_t vt[128][68];
  __shared__ ushort_t rs[32][136];
  __shared__ float    sA[4][12][36];
  __shared__ float    sB[4][12][36];
  __shared__ ushort_t Pp[4][16][40];

  const int base = n0*CHUNK - PAST;
  {
    const int r0 = tid >> 4;
    const int c0 = (tid & 15) * 8;
    for (int r = r0; r < 68; r += 16){
      int s = base + r;
      short8 kv = (short8)0, vv = (short8)0;
      if (r < 60 && s >= 0 && s < S){
        kv = *(const short8*)&qkv[(bS + s)*QKVW + 1024 + h*DH + c0];
        vv = *(const short8*)&qkv[(bS + s)*QKVW + 2048 + h*DH + c0];
      }
      *(short8*)&ks[r][c0] = kv;
#pragma unroll
      for (int u=0;u<8;u++) vt[c0+u][r] = (ushort_t)vv[u];
    }
    for (int r = r0; r < 32; r += 16){
      short8 rv = (short8)0;
      if (r < NPOS) rv = *(const short8*)&rel[r*HID + h*DH + c0];
      *(short8*)&rs[r][c0] = rv;
    }
  }
  __syncthreads();

  const int w    = tid >> 6;
  const int lane = tid & 63;
  const int lr   = lane & 15;
  const int lg   = lane >> 4;

  int qrow = (n0 + w)*CHUNK + lr;
  if (qrow >= S) qrow = S - 1;
  const ushort_t* qp = qkv + (bS + qrow)*QKVW + h*DH + lg*8;
  short8 qf[4];
#pragma unroll
  for (int ks2=0; ks2<4; ks2++) qf[ks2] = *(const short8*)(qp + ks2*32);

  // AC = q @ k^T
#pragma unroll
  for (int t0=0; t0<2; t0++){
    float4v acc = (float4v)0.0f;
#pragma unroll
    for (int ks2=0; ks2<4; ks2++){
      short8 kf = *(const short8*)&ks[w*CHUNK + t0*16 + lr][ks2*32 + lg*8];
      acc = __builtin_amdgcn_mfma_f32_16x16x32_bf16(qf[ks2], kf, acc, 0,0,0);
    }
#pragma unroll
    for (int reg=0; reg<4; reg++){
      int cr = lg*4 + reg;
      if (cr < CHUNK) sA[w][cr][t0*16 + lr] = acc[reg];
    }
  }

  // BD = q @ rel^T
#pragma unroll
  for (int t0=0; t0<2; t0++){
    float4v acc = (float4v)0.0f;
#pragma unroll
    for (int ks2=0; ks2<4; ks2++){
      short8 rf = *(const short8*)&rs[t0*16 + lr][ks2*32 + lg*8];
      acc = __builtin_amdgcn_mfma_f32_16x16x32_bf16(qf[ks2], rf, acc, 0,0,0);
    }
#pragma unroll
    for (int reg=0; reg<4; reg++){
      int cr = lg*4 + reg;
      if (cr < CHUNK) sB[w][cr][t0*16 + lr] = acc[reg];
    }
  }

#pragma unroll
  for (int i=0;i<2;i++){
    int idx = i*64 + lane;
    *(s4v*)&Pp[w][idx>>3][(idx&7)*4] = (s4v)0;
  }

  // rel-shift + softcap + softmax (wave-parallel)
  {
    const int c2 = lane >> 5;
    const int t  = lane & 31;
#pragma unroll
    for (int i=0;i<6;i++){
      int c = i*2 + c2;
      float x = -1e30f;
      if (t < CTX){
        int f = c*CTX + t;
        int r = f / NPOS, p = f - r*NPOS;
        x = sA[w][c][t] + sB[w][r][p];
        x = 50.0f * tanhf(x * 0.02f);
      }
      float m = x;
      for (int off=16; off>=1; off>>=1) m = fmaxf(m, __shfl_xor(m, off, 32));
      float e = (t < CTX) ? expf(x - m) : 0.0f;
      float s = e;
      for (int off=16; off>=1; off>>=1) s += __shfl_xor(s, off, 32);
      if (t < CTX) Pp[w][c][t] = f2bf(e / s);
    }
  }

  // PV: O[12x128] = P @ V
  short8 pf = *(const short8*)&Pp[w][lr][lg*8];
  const int orow_base = (n0 + w)*CHUNK;
#pragma unroll
  for (int j=0; j<8; j++){
    int d  = j*16 + lr;
    int tb = w*CHUNK + lg*8;
    s4v b0 = *(const s4v*)&vt[d][tb];
    s4v b1 = *(const s4v*)&vt[d][tb+4];
    short8 bf;
#pragma unroll
    for (int u=0;u<4;u++){ bf[u] = b0[u]; bf[u+4] = b1[u]; }
    float4v a = __builtin_amdgcn_mfma_f32_16x16x32_bf16(pf, bf, (float4v)0.0f, 0,0,0);
#pragma unroll
    for (int reg=0; reg<4; reg++){
      int cr = lg*4 + reg;
      if (cr < CHUNK)
        o[(bS + orow_base + cr)*HID + h*DH + j*16 + lr] = f2bf(a[reg]);
    }
  }
}

extern "C" void kernel_launch(void* const* d_in, const int* in_sizes, int n_in,
                              void* d_out, int out_size, void* d_ws, size_t ws_size,
                              hipStream_t stream)
{
  const float* hs    = (const float*)d_in[0];
  const float* pe    = (const float*)d_in[1];
  const float* Wq    = (const float*)d_in[2];
  const float* Wk    = (const float*)d_in[3];
  const float* Wv    = (const float*)d_in[4];
  const float* Wpost = (const float*)d_in[5];
  const float* Wrel  = (const float*)d_in[6];
  const float* pds   = (const float*)d_in[7];
  float* out = (float*)d_out;

  const int BS = in_sizes[0] / HID;   // 24576
  const int B  = 4;
  const int S  = BS / B;              // 6144
  const int nb = S / CHUNK;           // 512

  const size_t per = (size_t)BS * HID;
  const size_t wsz = (size_t)HID * HID;
  ushort_t* qkv  = (ushort_t*)d_ws;            // BS * 3072
  ushort_t* at   = qkv  + (size_t)BS * QKVW;   // BS * 1024
  ushort_t* rel  = at   + per;                 // 25 * 1024
  ushort_t* hsb  = rel  + (size_t)NPOS*HID;    // BS * 1024
  ushort_t* Wcat = hsb  + per;                 // 3072 * 1024 (Wq|Wk|Wv rows)
  ushort_t* Wpb  = Wcat + 3*wsz;               // 1024 * 1024

  const float qsc = (float)(pow((double)DH, -0.5) / log(2.0));   // D^-0.5/ln2
  const float ksc = (float)(log(1.0 + exp(1.0)) / log(2.0));     // ln(1+e)/ln2

  cvt_f2b<<<2048, 256, 0, stream>>>(hs, hsb, (int)(per/4));
  cvt_w4<<<2048, 256, 0, stream>>>(Wq, Wk, Wv, Wpost, Wcat, Wpb, (int)(wsz/4));

  // fused QKV projection: [24576,1024] @ [3072,1024]^T -> qkv[24576,3072]
  gemm8v2<1,0><<<(BS/256)*(QKVW/256), 512, 0, stream>>>(
      hsb, Wcat, qkv, BS, QKVW, HID, pds, qsc, ksc);
  relk_kernel<<<(NPOS*HID + 255)/256, 256, 0, stream>>>(pe, Wrel, rel);
  attn_kernel<<<dim3(nb/4, B, NH), 256, 0, stream>>>(qkv, rel, at, S);
  // output projection: [24576,1024] @ [1024,1024]^T -> out (f32)
  gemm2<0,1><<<(BS/128)*(HID/128), 256, 0, stream>>>(
      at, Wpb, out, BS, HID, HID, nullptr, 1.0f, 1.0f);
}

// Round 8
// 433.409 us; speedup vs baseline: 1.7948x; 1.0154x over previous
//
#include <hip/hip_runtime.h>
#include <hip/hip_bf16.h>
#include <math.h>

typedef unsigned short ushort_t;
typedef __attribute__((ext_vector_type(8))) short short8;
typedef __attribute__((ext_vector_type(4))) short s4v;
typedef __attribute__((ext_vector_type(4))) float float4v;

#define HID 1024
#define NH 8
#define DH 128
#define CHUNK 12
#define PAST 12
#define CTX 24
#define NPOS 25
#define QKVW 3072

__device__ __forceinline__ float bf2f(ushort_t b){
  union{unsigned int u; float f;} x; x.u = ((unsigned int)b)<<16; return x.f;
}
__device__ __forceinline__ ushort_t f2bf(float f){
  union{float f; unsigned int u;} x; x.f = f;
  unsigned int u = x.u;
  unsigned int r = u + 0x7fffu + ((u>>16)&1u);
  return (ushort_t)(r>>16);
}

// async global->LDS, 16B per lane; LDS dest = wave-uniform base + lane*16
__device__ __forceinline__ void gload16(const ushort_t* g, ushort_t* l){
  __builtin_amdgcn_global_load_lds(
      (const __attribute__((address_space(1))) unsigned int*)g,
      (__attribute__((address_space(3))) unsigned int*)l,
      16, 0, 0);
}

// f32 -> bf16 conversion, vectorized, grid-stride (n4 = elems/4)
__global__ __launch_bounds__(256) void cvt_f2b(
    const float* __restrict__ in, ushort_t* __restrict__ out, int n4)
{
  for (int i = blockIdx.x*256 + threadIdx.x; i < n4; i += gridDim.x*256){
    float4v v = ((const float4v*)in)[i];
    s4v o;
#pragma unroll
    for (int j=0;j<4;j++) o[j] = (short)f2bf(v[j]);
    ((s4v*)out)[i] = o;
  }
}

// all 4 weights in one launch: Wq|Wk|Wv -> Wcat, Wpost -> Wpb (each wsz elems)
__global__ __launch_bounds__(256) void cvt_w4(
    const float* __restrict__ Wq, const float* __restrict__ Wk,
    const float* __restrict__ Wv, const float* __restrict__ Wp,
    ushort_t* __restrict__ Wcat, ushort_t* __restrict__ Wpb, int wsz4)
{
  for (int i = blockIdx.x*256 + threadIdx.x; i < 4*wsz4; i += gridDim.x*256){
    int seg = i / wsz4, off = i - seg*wsz4;
    const float* src = (seg==0) ? Wq : (seg==1) ? Wk : (seg==2) ? Wv : Wp;
    float4v v = ((const float4v*)src)[off];
    s4v o;
#pragma unroll
    for (int j=0;j<4;j++) o[j] = (short)f2bf(v[j]);
    if (seg < 3) ((s4v*)Wcat)[seg*wsz4 + off] = o;
    else         ((s4v*)Wpb)[off] = o;
  }
}

// ===== 128x128 BK=32 2-phase GEMM with LDS-coalesced epilogue =====
// C[M,N] = A[M,K] @ W[N,K]^T  (bf16 in, f32 accum). 4 waves.
// Staging LDS (32KB) re-aliased as the C-tile at epilogue (no extra LDS).
// MODE: 0 = none, 1 = fused qkv epilogue. OUTF: 0 = bf16 out, 1 = f32 out.
template<int MODE, int OUTF>
__global__ __launch_bounds__(256) void gemm2(
    const ushort_t* __restrict__ A, const ushort_t* __restrict__ W,
    void* __restrict__ Cv, int M, int N, int K,
    const float* __restrict__ pds, float qsc, float ksc)
{
  const int nwg  = gridDim.x;
  const int orig = blockIdx.x;
  const int qch  = nwg >> 3, rch = nwg & 7;
  const int xcd  = orig & 7, idx = orig >> 3;
  const int bid  = (xcd < rch ? xcd*(qch+1) : rch*(qch+1) + (xcd-rch)*qch) + idx;

  const int NT = N >> 7;
  const int m0 = (bid / NT) * 128;
  const int n0 = (bid % NT) * 128;

  const int tid  = threadIdx.x;
  const int w    = tid >> 6, lane = tid & 63;
  const int wm   = w >> 1, wn = w & 1;
  const int lr   = lane & 15;
  const int lg   = lane >> 4;

  __shared__ ushort_t smem[4*128*32];          // 32KB: staging ring / C-tile
  ushort_t* As0 = smem;
  ushort_t* Bs0 = smem + 128*32;
  ushort_t* As1 = smem + 2*128*32;
  ushort_t* Bs1 = smem + 3*128*32;

  float4v acc[4][4];
#pragma unroll
  for (int i=0;i<4;i++)
#pragma unroll
    for (int j=0;j<4;j++) acc[i][j] = (float4v)0.0f;

  const int sr = lane >> 2;
  const int sc = (lane & 3) * 8;

  const ushort_t* Ab0 = A + (size_t)(m0 + w*16      + sr)*K + sc;
  const ushort_t* Ab1 = A + (size_t)(m0 + 64 + w*16 + sr)*K + sc;
  const ushort_t* Bb0 = W + (size_t)(n0 + w*16      + sr)*K + sc;
  const ushort_t* Bb1 = W + (size_t)(n0 + 64 + w*16 + sr)*K + sc;

#define STAGE(Abuf, Bbuf, kt) do {                    \
    gload16(Ab0 + (kt), &(Abuf)[(w*16)*32]);          \
    gload16(Ab1 + (kt), &(Abuf)[(64 + w*16)*32]);     \
    gload16(Bb0 + (kt), &(Bbuf)[(w*16)*32]);          \
    gload16(Bb1 + (kt), &(Bbuf)[(64 + w*16)*32]);     \
  } while(0)

#define COMPUTE(Abuf, Bbuf) do {                                             \
    short8 afr[4], bfr[4];                                                   \
    _Pragma("unroll")                                                        \
    for (int i=0;i<4;i++) afr[i] = *(const short8*)&(Abuf)[(wm*64 + i*16 + lr)*32 + lg*8]; \
    _Pragma("unroll")                                                        \
    for (int j=0;j<4;j++) bfr[j] = *(const short8*)&(Bbuf)[(wn*64 + j*16 + lr)*32 + lg*8]; \
    _Pragma("unroll")                                                        \
    for (int i=0;i<4;i++)                                                    \
      _Pragma("unroll")                                                      \
      for (int j=0;j<4;j++)                                                  \
        acc[i][j] = __builtin_amdgcn_mfma_f32_16x16x32_bf16(afr[i], bfr[j], acc[i][j], 0,0,0); \
  } while(0)

  const int nt = K >> 5;
  STAGE(As0, Bs0, 0);
  __syncthreads();

  for (int t = 0; t < nt; t += 2){
    if (t+1 < nt) STAGE(As1, Bs1, (t+1)*32);
    COMPUTE(As0, Bs0);
    __syncthreads();
    if (t+2 < nt) STAGE(As0, Bs0, (t+2)*32);
    COMPUTE(As1, Bs1);
    __syncthreads();
  }
#undef STAGE
#undef COMPUTE

  // ---- epilogue: scale, stage C-tile in LDS, stream coalesced ----
  if (OUTF == 0){
    // bf16 out: full 128x128 bf16 tile = 32KB (aliases staging, reads done)
#pragma unroll
    for (int j=0;j<4;j++){
      const int col = wn*64 + j*16 + lr;
      float scale = 1.0f;
      if (MODE==1){
        const int gcol = n0 + col;
        if (gcol < 1024){ float p = pds[gcol & (DH-1)]; scale = qsc * log1pf(expf(p)); }
        else if (gcol < 2048) scale = ksc;
      }
#pragma unroll
      for (int i=0;i<4;i++){
        const int row = wm*64 + i*16 + lg*4;
#pragma unroll
        for (int r=0;r<4;r++)
          smem[(row + r)*128 + col] = f2bf(acc[i][j][r] * scale);
      }
    }
    __syncthreads();
    // stream: 16 rows/iter, 16 lanes/row x short8 (256B contiguous per row)
    ushort_t* Crow = (ushort_t*)Cv + (size_t)m0*N + n0;
    const int rr = tid >> 4, sl = (tid & 15)*8;
#pragma unroll
    for (int it=0; it<8; ++it){
      const int row = it*16 + rr;
      *(short8*)&Crow[(size_t)row*N + sl] = *(const short8*)&smem[row*128 + sl];
    }
  } else {
    // f32 out: two 64-row halves (each 64x128 f32 = 32KB)
    float* smf = (float*)smem;
    float* Crow = (float*)Cv + (size_t)m0*N + n0;
#pragma unroll
    for (int h2=0; h2<2; ++h2){
      __syncthreads();
      if (wm == h2){
#pragma unroll
        for (int j=0;j<4;j++){
          const int col = wn*64 + j*16 + lr;
#pragma unroll
          for (int i=0;i<4;i++){
            const int row = i*16 + lg*4;   // local row within half
#pragma unroll
            for (int r=0;r<4;r++)
              smf[(row + r)*128 + col] = acc[i][j][r];
          }
        }
      }
      __syncthreads();
      // stream 64 rows x 512B: 8 rows/iter? -> 16 lanes x float4 cover 64 cols
      const int rr = tid >> 5, half = ((tid >> 4) & 1)*64, sl = (tid & 15)*4;
#pragma unroll
      for (int it=0; it<8; ++it){
        const int row = it*8 + rr;         // 8 rows per iter
        *(float4v*)&Crow[(size_t)(h2*64 + row)*N + half + sl] =
            *(const float4v*)&smf[row*128 + half + sl];
      }
    }
  }
}

// rel[25,1024] = pos_emb[25,1024] @ Wrel[1024,1024]^T   (f32 in, bf16 out)
__global__ __launch_bounds__(256) void relk_kernel(
    const float* __restrict__ pe, const float* __restrict__ Wrel,
    ushort_t* __restrict__ rel)
{
  int gid = blockIdx.x*256 + threadIdx.x;
  if (gid >= NPOS*HID) return;
  int p = gid >> 10, n = gid & 1023;
  const float* a = pe + p*HID;
  const float* w = Wrel + (size_t)n*HID;
  float s = 0.f;
  for (int k=0;k<HID;k+=4){
    float4v av = *(const float4v*)(a+k);
    float4v wv = *(const float4v*)(w+k);
#pragma unroll
    for (int u=0;u<4;u++) s += av[u]*wv[u];
  }
  rel[gid] = f2bf(s);
}

// MFMA attention on fused qkv[row][3072] (q:0, k:+1024, v:+2048).
// block = 4 waves = 4 consecutive chunks of one (b,h).
__global__ __launch_bounds__(256) void attn_kernel(
  const ushort_t* __restrict__ qkv, const ushort_t* __restrict__ rel,
  ushort_t* __restrict__ o, int S)
{
  const int n0 = blockIdx.x * 4;
  const int b  = blockIdx.y, h = blockIdx.z;
  const int tid = threadIdx.x;
  const size_t bS = (size_t)b * S;

  __shared__ ushort_t ks[68][136];
  __shared__ ushort_t vt[128][68];
  __shared__ ushort_t rs[32][136];
  __shared__ float    sA[4][12][36];
  __shared__ float    sB[4][12][36];
  __shared__ ushort_t Pp[4][16][40];

  const int base = n0*CHUNK - PAST;
  {
    const int r0 = tid >> 4;
    const int c0 = (tid & 15) * 8;
    for (int r = r0; r < 68; r += 16){
      int s = base + r;
      short8 kv = (short8)0, vv = (short8)0;
      if (r < 60 && s >= 0 && s < S){
        kv = *(const short8*)&qkv[(bS + s)*QKVW + 1024 + h*DH + c0];
        vv = *(const short8*)&qkv[(bS + s)*QKVW + 2048 + h*DH + c0];
      }
      *(short8*)&ks[r][c0] = kv;
#pragma unroll
      for (int u=0;u<8;u++) vt[c0+u][r] = (ushort_t)vv[u];
    }
    for (int r = r0; r < 32; r += 16){
      short8 rv = (short8)0;
      if (r < NPOS) rv = *(const short8*)&rel[r*HID + h*DH + c0];
      *(short8*)&rs[r][c0] = rv;
    }
  }
  __syncthreads();

  const int w    = tid >> 6;
  const int lane = tid & 63;
  const int lr   = lane & 15;
  const int lg   = lane >> 4;

  int qrow = (n0 + w)*CHUNK + lr;
  if (qrow >= S) qrow = S - 1;
  const ushort_t* qp = qkv + (bS + qrow)*QKVW + h*DH + lg*8;
  short8 qf[4];
#pragma unroll
  for (int ks2=0; ks2<4; ks2++) qf[ks2] = *(const short8*)(qp + ks2*32);

  // AC = q @ k^T
#pragma unroll
  for (int t0=0; t0<2; t0++){
    float4v acc = (float4v)0.0f;
#pragma unroll
    for (int ks2=0; ks2<4; ks2++){
      short8 kf = *(const short8*)&ks[w*CHUNK + t0*16 + lr][ks2*32 + lg*8];
      acc = __builtin_amdgcn_mfma_f32_16x16x32_bf16(qf[ks2], kf, acc, 0,0,0);
    }
#pragma unroll
    for (int reg=0; reg<4; reg++){
      int cr = lg*4 + reg;
      if (cr < CHUNK) sA[w][cr][t0*16 + lr] = acc[reg];
    }
  }

  // BD = q @ rel^T
#pragma unroll
  for (int t0=0; t0<2; t0++){
    float4v acc = (float4v)0.0f;
#pragma unroll
    for (int ks2=0; ks2<4; ks2++){
      short8 rf = *(const short8*)&rs[t0*16 + lr][ks2*32 + lg*8];
      acc = __builtin_amdgcn_mfma_f32_16x16x32_bf16(qf[ks2], rf, acc, 0,0,0);
    }
#pragma unroll
    for (int reg=0; reg<4; reg++){
      int cr = lg*4 + reg;
      if (cr < CHUNK) sB[w][cr][t0*16 + lr] = acc[reg];
    }
  }

#pragma unroll
  for (int i=0;i<2;i++){
    int idx = i*64 + lane;
    *(s4v*)&Pp[w][idx>>3][(idx&7)*4] = (s4v)0;
  }

  // rel-shift + softcap + softmax (wave-parallel)
  {
    const int c2 = lane >> 5;
    const int t  = lane & 31;
#pragma unroll
    for (int i=0;i<6;i++){
      int c = i*2 + c2;
      float x = -1e30f;
      if (t < CTX){
        int f = c*CTX + t;
        int r = f / NPOS, p = f - r*NPOS;
        x = sA[w][c][t] + sB[w][r][p];
        x = 50.0f * tanhf(x * 0.02f);
      }
      float m = x;
      for (int off=16; off>=1; off>>=1) m = fmaxf(m, __shfl_xor(m, off, 32));
      float e = (t < CTX) ? expf(x - m) : 0.0f;
      float s = e;
      for (int off=16; off>=1; off>>=1) s += __shfl_xor(s, off, 32);
      if (t < CTX) Pp[w][c][t] = f2bf(e / s);
    }
  }

  // PV: O[12x128] = P @ V
  short8 pf = *(const short8*)&Pp[w][lr][lg*8];
  const int orow_base = (n0 + w)*CHUNK;
#pragma unroll
  for (int j=0; j<8; j++){
    int d  = j*16 + lr;
    int tb = w*CHUNK + lg*8;
    s4v b0 = *(const s4v*)&vt[d][tb];
    s4v b1 = *(const s4v*)&vt[d][tb+4];
    short8 bf;
#pragma unroll
    for (int u=0;u<4;u++){ bf[u] = b0[u]; bf[u+4] = b1[u]; }
    float4v a = __builtin_amdgcn_mfma_f32_16x16x32_bf16(pf, bf, (float4v)0.0f, 0,0,0);
#pragma unroll
    for (int reg=0; reg<4; reg++){
      int cr = lg*4 + reg;
      if (cr < CHUNK)
        o[(bS + orow_base + cr)*HID + h*DH + j*16 + lr] = f2bf(a[reg]);
    }
  }
}

extern "C" void kernel_launch(void* const* d_in, const int* in_sizes, int n_in,
                              void* d_out, int out_size, void* d_ws, size_t ws_size,
                              hipStream_t stream)
{
  const float* hs    = (const float*)d_in[0];
  const float* pe    = (const float*)d_in[1];
  const float* Wq    = (const float*)d_in[2];
  const float* Wk    = (const float*)d_in[3];
  const float* Wv    = (const float*)d_in[4];
  const float* Wpost = (const float*)d_in[5];
  const float* Wrel  = (const float*)d_in[6];
  const float* pds   = (const float*)d_in[7];
  float* out = (float*)d_out;

  const int BS = in_sizes[0] / HID;   // 24576
  const int B  = 4;
  const int S  = BS / B;              // 6144
  const int nb = S / CHUNK;           // 512

  const size_t per = (size_t)BS * HID;
  const size_t wsz = (size_t)HID * HID;
  ushort_t* qkv  = (ushort_t*)d_ws;            // BS * 3072
  ushort_t* at   = qkv  + (size_t)BS * QKVW;   // BS * 1024
  ushort_t* rel  = at   + per;                 // 25 * 1024
  ushort_t* hsb  = rel  + (size_t)NPOS*HID;    // BS * 1024
  ushort_t* Wcat = hsb  + per;                 // 3072 * 1024 (Wq|Wk|Wv rows)
  ushort_t* Wpb  = Wcat + 3*wsz;               // 1024 * 1024

  const float qsc = (float)(pow((double)DH, -0.5) / log(2.0));   // D^-0.5/ln2
  const float ksc = (float)(log(1.0 + exp(1.0)) / log(2.0));     // ln(1+e)/ln2

  cvt_f2b<<<2048, 256, 0, stream>>>(hs, hsb, (int)(per/4));
  cvt_w4<<<2048, 256, 0, stream>>>(Wq, Wk, Wv, Wpost, Wcat, Wpb, (int)(wsz/4));

  // fused QKV projection: [24576,1024] @ [3072,1024]^T -> qkv[24576,3072]
  gemm2<1,0><<<(BS/128)*(QKVW/128), 256, 0, stream>>>(
      hsb, Wcat, qkv, BS, QKVW, HID, pds, qsc, ksc);
  relk_kernel<<<(NPOS*HID + 255)/256, 256, 0, stream>>>(pe, Wrel, rel);
  attn_kernel<<<dim3(nb/4, B, NH), 256, 0, stream>>>(qkv, rel, at, S);
  // output projection: [24576,1024] @ [1024,1024]^T -> out (f32)
  gemm2<0,1><<<(BS/128)*(HID/128), 256, 0, stream>>>(
      at, Wpb, out, BS, HID, HID, nullptr, 1.0f, 1.0f);
}

// Round 9
// 423.364 us; speedup vs baseline: 1.8374x; 1.0237x over previous
//
#include <hip/hip_runtime.h>
#include <hip/hip_bf16.h>
#include <math.h>

typedef unsigned short ushort_t;
typedef __attribute__((ext_vector_type(8))) short short8;
typedef __attribute__((ext_vector_type(4))) short s4v;
typedef __attribute__((ext_vector_type(4))) float float4v;

#define HID 1024
#define NH 8
#define DH 128
#define CHUNK 12
#define PAST 12
#define CTX 24
#define NPOS 25
#define QKVW 3072

__device__ __forceinline__ float bf2f(ushort_t b){
  union{unsigned int u; float f;} x; x.u = ((unsigned int)b)<<16; return x.f;
}
__device__ __forceinline__ ushort_t f2bf(float f){
  union{float f; unsigned int u;} x; x.f = f;
  unsigned int u = x.u;
  unsigned int r = u + 0x7fffu + ((u>>16)&1u);
  return (ushort_t)(r>>16);
}

__device__ __forceinline__ void gload16(const ushort_t* g, ushort_t* l){
  __builtin_amdgcn_global_load_lds(
      (const __attribute__((address_space(1))) unsigned int*)g,
      (__attribute__((address_space(3))) unsigned int*)l,
      16, 0, 0);
}

// f32 -> bf16 conversion, vectorized, grid-stride (n4 = elems/4)
__global__ __launch_bounds__(256) void cvt_f2b(
    const float* __restrict__ in, ushort_t* __restrict__ out, int n4)
{
  for (int i = blockIdx.x*256 + threadIdx.x; i < n4; i += gridDim.x*256){
    float4v v = ((const float4v*)in)[i];
    s4v o;
#pragma unroll
    for (int j=0;j<4;j++) o[j] = (short)f2bf(v[j]);
    ((s4v*)out)[i] = o;
  }
}

// all 4 weights in one launch
__global__ __launch_bounds__(256) void cvt_w4(
    const float* __restrict__ Wq, const float* __restrict__ Wk,
    const float* __restrict__ Wv, const float* __restrict__ Wp,
    ushort_t* __restrict__ Wcat, ushort_t* __restrict__ Wpb, int wsz4)
{
  for (int i = blockIdx.x*256 + threadIdx.x; i < 4*wsz4; i += gridDim.x*256){
    int seg = i / wsz4, off = i - seg*wsz4;
    const float* src = (seg==0) ? Wq : (seg==1) ? Wk : (seg==2) ? Wv : Wp;
    float4v v = ((const float4v*)src)[off];
    s4v o;
#pragma unroll
    for (int j=0;j<4;j++) o[j] = (short)f2bf(v[j]);
    if (seg < 3) ((s4v*)Wcat)[seg*wsz4 + off] = o;
    else         ((s4v*)Wpb)[off] = o;
  }
}

// ====== 256x256 BK=32 counted-vmcnt pipelined GEMM (T3+T4+T5) ======
// C[M,N] = A[M,K] @ W[N,K]^T, bf16 in, f32 accum, bf16 out (coalesced).
// 512 thr = 8 waves (2m x 4n); wave out = 128x64. LDS: 4-slot ring,
// slot = A[256x32] + B[256x32] = 32KB (128KB total), tile t -> slot t&3.
// Stage lead = 2 tiles (4 gload16/thread/tile). Per tile:
//   vmcnt(4) [vmcnt(0) only at last tile]; s_barrier;
//   stage A(t+2); read B(4)+A(4); 16 MFMA; s_barrier;
//   stage B(t+2); read A(4); 16 MFMA.
// Ledger: steady outstanding at tile entry = 8 (t+1:4, t+2 staged during t);
// vmcnt(4) retires exactly tile t's loads. Never 0 until the tail.
template<int MODE>
__global__ __launch_bounds__(512) void gemmp(
    const ushort_t* __restrict__ A, const ushort_t* __restrict__ W,
    ushort_t* __restrict__ C, int M, int N, int K,
    const float* __restrict__ pds, float qsc, float ksc)
{
  const int nwg = gridDim.x, orig = blockIdx.x;
  const int qch = nwg >> 3, rch = nwg & 7;
  const int xcd = orig & 7, idx = orig >> 3;
  const int bid = (xcd < rch ? xcd*(qch+1) : rch*(qch+1) + (xcd-rch)*qch) + idx;

  const int NT = N >> 8;
  const int m0 = (bid / NT) * 256;
  const int n0 = (bid % NT) * 256;

  const int tid = threadIdx.x;
  const int w = tid >> 6, lane = tid & 63;
  const int wm = w >> 2, wn = w & 3;
  const int lr = lane & 15, lg = lane >> 4;

  __shared__ ushort_t ring[4][16384];   // slot: A at 0, B at 8192 (elems)

  float4v acc[8][4];
#pragma unroll
  for (int i=0;i<8;i++)
#pragma unroll
    for (int j=0;j<4;j++) acc[i][j] = (float4v)0.0f;

  // staging: round covers 128 rows (512thr x 16B); per wave 16 rows.
  const int srow = lane >> 2;          // 0..15
  const int sofs = (lane & 3) * 8;     // elems
  const ushort_t* Ag0 = A + (size_t)(m0 +       w*16 + srow)*K + sofs;
  const ushort_t* Ag1 = A + (size_t)(m0 + 128 + w*16 + srow)*K + sofs;
  const ushort_t* Bg0 = W + (size_t)(n0 +       w*16 + srow)*K + sofs;
  const ushort_t* Bg1 = W + (size_t)(n0 + 128 + w*16 + srow)*K + sofs;

#define STAGE_A(slot, kt) do{                                  \
    gload16(Ag0 + (kt), &ring[slot][(w*16)*32]);               \
    gload16(Ag1 + (kt), &ring[slot][(128 + w*16)*32]); }while(0)
#define STAGE_B(slot, kt) do{                                  \
    gload16(Bg0 + (kt), &ring[slot][8192 + (w*16)*32]);        \
    gload16(Bg1 + (kt), &ring[slot][8192 + (128 + w*16)*32]); }while(0)

  const int T = K >> 5;                // 32 K-tiles for K=1024
  STAGE_A(0, 0);  STAGE_B(0, 0);
  STAGE_A(1, 32); STAGE_B(1, 32);

  for (int t = 0; t < T; ++t){
    const int s  = t & 3;
    const int ns = (t+2) & 3;
    const int k2 = (t+2) << 5;
    const bool pf = (t+2 < T);

    if (t == T-1) asm volatile("s_waitcnt vmcnt(0)" ::: "memory");
    else          asm volatile("s_waitcnt vmcnt(4)" ::: "memory");
    asm volatile("s_barrier" ::: "memory");

    if (pf) STAGE_A(ns, k2);

    short8 bfr[4];
#pragma unroll
    for (int j=0;j<4;j++)
      bfr[j] = *(const short8*)&ring[s][8192 + (wn*64 + j*16 + lr)*32 + lg*8];
    {
      short8 afr[4];
#pragma unroll
      for (int i=0;i<4;i++)
        afr[i] = *(const short8*)&ring[s][(wm*128 + i*16 + lr)*32 + lg*8];
      __builtin_amdgcn_s_setprio(1);
#pragma unroll
      for (int i=0;i<4;i++)
#pragma unroll
        for (int j=0;j<4;j++)
          acc[i][j] = __builtin_amdgcn_mfma_f32_16x16x32_bf16(afr[i], bfr[j], acc[i][j], 0,0,0);
      __builtin_amdgcn_s_setprio(0);
    }
    asm volatile("s_barrier" ::: "memory");

    if (pf) STAGE_B(ns, k2);
    {
      short8 afr[4];
#pragma unroll
      for (int i=0;i<4;i++)
        afr[i] = *(const short8*)&ring[s][(wm*128 + 64 + i*16 + lr)*32 + lg*8];
      __builtin_amdgcn_s_setprio(1);
#pragma unroll
      for (int i=0;i<4;i++)
#pragma unroll
        for (int j=0;j<4;j++)
          acc[4+i][j] = __builtin_amdgcn_mfma_f32_16x16x32_bf16(afr[i], bfr[j], acc[4+i][j], 0,0,0);
      __builtin_amdgcn_s_setprio(0);
    }
  }
#undef STAGE_A
#undef STAGE_B

  // ---- epilogue: C-tile in LDS (aliases ring, 256x256 bf16 = 128KB) ----
  asm volatile("s_barrier" ::: "memory");   // all waves' ds_reads drained (via MFMA deps)
  ushort_t* Ct = &ring[0][0];
#pragma unroll
  for (int j=0;j<4;j++){
    const int col = wn*64 + j*16 + lr;
    float scale = 1.0f;
    if (MODE==1){
      const int gcol = n0 + col;
      if (gcol < 1024){ float p = pds[gcol & (DH-1)]; scale = qsc * log1pf(expf(p)); }
      else if (gcol < 2048) scale = ksc;
    }
#pragma unroll
    for (int i=0;i<8;i++){
      const int row = wm*128 + i*16 + lg*4;
#pragma unroll
      for (int r=0;r<4;r++)
        Ct[(row + r)*256 + col] = f2bf(acc[i][j][r] * scale);
    }
  }
  asm volatile("s_barrier" ::: "memory");
  ushort_t* Crow = C + (size_t)m0*N + n0;
  const int rr = tid >> 5, sl = (tid & 31)*8;
#pragma unroll
  for (int it=0; it<16; ++it){
    const int row = it*16 + rr;
    *(short8*)&Crow[(size_t)row*N + sl] = *(const short8*)&Ct[row*256 + sl];
  }
}

// ===== 128x128 BK=32 2-phase GEMM with LDS-coalesced epilogue (out-proj) =====
template<int MODE, int OUTF>
__global__ __launch_bounds__(256) void gemm2(
    const ushort_t* __restrict__ A, const ushort_t* __restrict__ W,
    void* __restrict__ Cv, int M, int N, int K,
    const float* __restrict__ pds, float qsc, float ksc)
{
  const int nwg  = gridDim.x;
  const int orig = blockIdx.x;
  const int qch  = nwg >> 3, rch = nwg & 7;
  const int xcd  = orig & 7, idx = orig >> 3;
  const int bid  = (xcd < rch ? xcd*(qch+1) : rch*(qch+1) + (xcd-rch)*qch) + idx;

  const int NT = N >> 7;
  const int m0 = (bid / NT) * 128;
  const int n0 = (bid % NT) * 128;

  const int tid  = threadIdx.x;
  const int w    = tid >> 6, lane = tid & 63;
  const int wm   = w >> 1, wn = w & 1;
  const int lr   = lane & 15;
  const int lg   = lane >> 4;

  __shared__ ushort_t smem[4*128*32];
  ushort_t* As0 = smem;
  ushort_t* Bs0 = smem + 128*32;
  ushort_t* As1 = smem + 2*128*32;
  ushort_t* Bs1 = smem + 3*128*32;

  float4v acc[4][4];
#pragma unroll
  for (int i=0;i<4;i++)
#pragma unroll
    for (int j=0;j<4;j++) acc[i][j] = (float4v)0.0f;

  const int sr = lane >> 2;
  const int sc = (lane & 3) * 8;

  const ushort_t* Ab0 = A + (size_t)(m0 + w*16      + sr)*K + sc;
  const ushort_t* Ab1 = A + (size_t)(m0 + 64 + w*16 + sr)*K + sc;
  const ushort_t* Bb0 = W + (size_t)(n0 + w*16      + sr)*K + sc;
  const ushort_t* Bb1 = W + (size_t)(n0 + 64 + w*16 + sr)*K + sc;

#define STAGE(Abuf, Bbuf, kt) do {                    \
    gload16(Ab0 + (kt), &(Abuf)[(w*16)*32]);          \
    gload16(Ab1 + (kt), &(Abuf)[(64 + w*16)*32]);     \
    gload16(Bb0 + (kt), &(Bbuf)[(w*16)*32]);          \
    gload16(Bb1 + (kt), &(Bbuf)[(64 + w*16)*32]);     \
  } while(0)

#define COMPUTE(Abuf, Bbuf) do {                                             \
    short8 afr[4], bfr[4];                                                   \
    _Pragma("unroll")                                                        \
    for (int i=0;i<4;i++) afr[i] = *(const short8*)&(Abuf)[(wm*64 + i*16 + lr)*32 + lg*8]; \
    _Pragma("unroll")                                                        \
    for (int j=0;j<4;j++) bfr[j] = *(const short8*)&(Bbuf)[(wn*64 + j*16 + lr)*32 + lg*8]; \
    _Pragma("unroll")                                                        \
    for (int i=0;i<4;i++)                                                    \
      _Pragma("unroll")                                                      \
      for (int j=0;j<4;j++)                                                  \
        acc[i][j] = __builtin_amdgcn_mfma_f32_16x16x32_bf16(afr[i], bfr[j], acc[i][j], 0,0,0); \
  } while(0)

  const int nt = K >> 5;
  STAGE(As0, Bs0, 0);
  __syncthreads();

  for (int t = 0; t < nt; t += 2){
    if (t+1 < nt) STAGE(As1, Bs1, (t+1)*32);
    COMPUTE(As0, Bs0);
    __syncthreads();
    if (t+2 < nt) STAGE(As0, Bs0, (t+2)*32);
    COMPUTE(As1, Bs1);
    __syncthreads();
  }
#undef STAGE
#undef COMPUTE

  if (OUTF == 0){
#pragma unroll
    for (int j=0;j<4;j++){
      const int col = wn*64 + j*16 + lr;
      float scale = 1.0f;
      if (MODE==1){
        const int gcol = n0 + col;
        if (gcol < 1024){ float p = pds[gcol & (DH-1)]; scale = qsc * log1pf(expf(p)); }
        else if (gcol < 2048) scale = ksc;
      }
#pragma unroll
      for (int i=0;i<4;i++){
        const int row = wm*64 + i*16 + lg*4;
#pragma unroll
        for (int r=0;r<4;r++)
          smem[(row + r)*128 + col] = f2bf(acc[i][j][r] * scale);
      }
    }
    __syncthreads();
    ushort_t* Crow = (ushort_t*)Cv + (size_t)m0*N + n0;
    const int rr = tid >> 4, sl = (tid & 15)*8;
#pragma unroll
    for (int it=0; it<8; ++it){
      const int row = it*16 + rr;
      *(short8*)&Crow[(size_t)row*N + sl] = *(const short8*)&smem[row*128 + sl];
    }
  } else {
    float* smf = (float*)smem;
    float* Crow = (float*)Cv + (size_t)m0*N + n0;
#pragma unroll
    for (int h2=0; h2<2; ++h2){
      __syncthreads();
      if (wm == h2){
#pragma unroll
        for (int j=0;j<4;j++){
          const int col = wn*64 + j*16 + lr;
#pragma unroll
          for (int i=0;i<4;i++){
            const int row = i*16 + lg*4;
#pragma unroll
            for (int r=0;r<4;r++)
              smf[(row + r)*128 + col] = acc[i][j][r];
          }
        }
      }
      __syncthreads();
      const int rr = tid >> 5, half = ((tid >> 4) & 1)*64, sl = (tid & 15)*4;
#pragma unroll
      for (int it=0; it<8; ++it){
        const int row = it*8 + rr;
        *(float4v*)&Crow[(size_t)(h2*64 + row)*N + half + sl] =
            *(const float4v*)&smf[row*128 + half + sl];
      }
    }
  }
}

// rel[25,1024] = pos_emb[25,1024] @ Wrel[1024,1024]^T   (f32 in, bf16 out)
__global__ __launch_bounds__(256) void relk_kernel(
    const float* __restrict__ pe, const float* __restrict__ Wrel,
    ushort_t* __restrict__ rel)
{
  int gid = blockIdx.x*256 + threadIdx.x;
  if (gid >= NPOS*HID) return;
  int p = gid >> 10, n = gid & 1023;
  const float* a = pe + p*HID;
  const float* w = Wrel + (size_t)n*HID;
  float s = 0.f;
  for (int k=0;k<HID;k+=4){
    float4v av = *(const float4v*)(a+k);
    float4v wv = *(const float4v*)(w+k);
#pragma unroll
    for (int u=0;u<4;u++) s += av[u]*wv[u];
  }
  rel[gid] = f2bf(s);
}

// MFMA attention on fused qkv[row][3072] (q:0, k:+1024, v:+2048).
__global__ __launch_bounds__(256) void attn_kernel(
  const ushort_t* __restrict__ qkv, const ushort_t* __restrict__ rel,
  ushort_t* __restrict__ o, int S)
{
  const int n0 = blockIdx.x * 4;
  const int b  = blockIdx.y, h = blockIdx.z;
  const int tid = threadIdx.x;
  const size_t bS = (size_t)b * S;

  __shared__ ushort_t ks[68][136];
  __shared__ ushort_t vt[128][68];
  __shared__ ushort_t rs[32][136];
  __shared__ float    sA[4][12][36];
  __shared__ float    sB[4][12][36];
  __shared__ ushort_t Pp[4][16][40];

  const int base = n0*CHUNK - PAST;
  {
    const int r0 = tid >> 4;
    const int c0 = (tid & 15) * 8;
    for (int r = r0; r < 68; r += 16){
      int s = base + r;
      short8 kv = (short8)0, vv = (short8)0;
      if (r < 60 && s >= 0 && s < S){
        kv = *(const short8*)&qkv[(bS + s)*QKVW + 1024 + h*DH + c0];
        vv = *(const short8*)&qkv[(bS + s)*QKVW + 2048 + h*DH + c0];
      }
      *(short8*)&ks[r][c0] = kv;
#pragma unroll
      for (int u=0;u<8;u++) vt[c0+u][r] = (ushort_t)vv[u];
    }
    for (int r = r0; r < 32; r += 16){
      short8 rv = (short8)0;
      if (r < NPOS) rv = *(const short8*)&rel[r*HID + h*DH + c0];
      *(short8*)&rs[r][c0] = rv;
    }
  }
  __syncthreads();

  const int w    = tid >> 6;
  const int lane = tid & 63;
  const int lr   = lane & 15;
  const int lg   = lane >> 4;

  int qrow = (n0 + w)*CHUNK + lr;
  if (qrow >= S) qrow = S - 1;
  const ushort_t* qp = qkv + (bS + qrow)*QKVW + h*DH + lg*8;
  short8 qf[4];
#pragma unroll
  for (int ks2=0; ks2<4; ks2++) qf[ks2] = *(const short8*)(qp + ks2*32);

#pragma unroll
  for (int t0=0; t0<2; t0++){
    float4v acc = (float4v)0.0f;
#pragma unroll
    for (int ks2=0; ks2<4; ks2++){
      short8 kf = *(const short8*)&ks[w*CHUNK + t0*16 + lr][ks2*32 + lg*8];
      acc = __builtin_amdgcn_mfma_f32_16x16x32_bf16(qf[ks2], kf, acc, 0,0,0);
    }
#pragma unroll
    for (int reg=0; reg<4; reg++){
      int cr = lg*4 + reg;
      if (cr < CHUNK) sA[w][cr][t0*16 + lr] = acc[reg];
    }
  }

#pragma unroll
  for (int t0=0; t0<2; t0++){
    float4v acc = (float4v)0.0f;
#pragma unroll
    for (int ks2=0; ks2<4; ks2++){
      short8 rf = *(const short8*)&rs[t0*16 + lr][ks2*32 + lg*8];
      acc = __builtin_amdgcn_mfma_f32_16x16x32_bf16(qf[ks2], rf, acc, 0,0,0);
    }
#pragma unroll
    for (int reg=0; reg<4; reg++){
      int cr = lg*4 + reg;
      if (cr < CHUNK) sB[w][cr][t0*16 + lr] = acc[reg];
    }
  }

#pragma unroll
  for (int i=0;i<2;i++){
    int idx = i*64 + lane;
    *(s4v*)&Pp[w][idx>>3][(idx&7)*4] = (s4v)0;
  }

  {
    const int c2 = lane >> 5;
    const int t  = lane & 31;
#pragma unroll
    for (int i=0;i<6;i++){
      int c = i*2 + c2;
      float x = -1e30f;
      if (t < CTX){
        int f = c*CTX + t;
        int r = f / NPOS, p = f - r*NPOS;
        x = sA[w][c][t] + sB[w][r][p];
        x = 50.0f * tanhf(x * 0.02f);
      }
      float m = x;
      for (int off=16; off>=1; off>>=1) m = fmaxf(m, __shfl_xor(m, off, 32));
      float e = (t < CTX) ? expf(x - m) : 0.0f;
      float s = e;
      for (int off=16; off>=1; off>>=1) s += __shfl_xor(s, off, 32);
      if (t < CTX) Pp[w][c][t] = f2bf(e / s);
    }
  }

  short8 pf = *(const short8*)&Pp[w][lr][lg*8];
  const int orow_base = (n0 + w)*CHUNK;
#pragma unroll
  for (int j=0; j<8; j++){
    int d  = j*16 + lr;
    int tb = w*CHUNK + lg*8;
    s4v b0 = *(const s4v*)&vt[d][tb];
    s4v b1 = *(const s4v*)&vt[d][tb+4];
    short8 bf;
#pragma unroll
    for (int u=0;u<4;u++){ bf[u] = b0[u]; bf[u+4] = b1[u]; }
    float4v a = __builtin_amdgcn_mfma_f32_16x16x32_bf16(pf, bf, (float4v)0.0f, 0,0,0);
#pragma unroll
    for (int reg=0; reg<4; reg++){
      int cr = lg*4 + reg;
      if (cr < CHUNK)
        o[(bS + orow_base + cr)*HID + h*DH + j*16 + lr] = f2bf(a[reg]);
    }
  }
}

extern "C" void kernel_launch(void* const* d_in, const int* in_sizes, int n_in,
                              void* d_out, int out_size, void* d_ws, size_t ws_size,
                              hipStream_t stream)
{
  const float* hs    = (const float*)d_in[0];
  const float* pe    = (const float*)d_in[1];
  const float* Wq    = (const float*)d_in[2];
  const float* Wk    = (const float*)d_in[3];
  const float* Wv    = (const float*)d_in[4];
  const float* Wpost = (const float*)d_in[5];
  const float* Wrel  = (const float*)d_in[6];
  const float* pds   = (const float*)d_in[7];
  float* out = (float*)d_out;

  const int BS = in_sizes[0] / HID;   // 24576
  const int B  = 4;
  const int S  = BS / B;              // 6144
  const int nb = S / CHUNK;           // 512

  const size_t per = (size_t)BS * HID;
  const size_t wsz = (size_t)HID * HID;
  ushort_t* qkv  = (ushort_t*)d_ws;
  ushort_t* at   = qkv  + (size_t)BS * QKVW;
  ushort_t* rel  = at   + per;
  ushort_t* hsb  = rel  + (size_t)NPOS*HID;
  ushort_t* Wcat = hsb  + per;
  ushort_t* Wpb  = Wcat + 3*wsz;

  const float qsc = (float)(pow((double)DH, -0.5) / log(2.0));
  const float ksc = (float)(log(1.0 + exp(1.0)) / log(2.0));

  cvt_f2b<<<2048, 256, 0, stream>>>(hs, hsb, (int)(per/4));
  cvt_w4<<<2048, 256, 0, stream>>>(Wq, Wk, Wv, Wpost, Wcat, Wpb, (int)(wsz/4));

  // fused QKV projection: pipelined 256^2 GEMM, 96x12 = 1152 blocks
  gemmp<1><<<(BS/256)*(QKVW/256), 512, 0, stream>>>(
      hsb, Wcat, qkv, BS, QKVW, HID, pds, qsc, ksc);
  relk_kernel<<<(NPOS*HID + 255)/256, 256, 0, stream>>>(pe, Wrel, rel);
  attn_kernel<<<dim3(nb/4, B, NH), 256, 0, stream>>>(qkv, rel, at, S);
  gemm2<0,1><<<(BS/128)*(HID/128), 256, 0, stream>>>(
      at, Wpb, out, BS, HID, HID, nullptr, 1.0f, 1.0f);
}